// Round 1
// baseline (1784.599 us; speedup 1.0000x reference)
//
#include <hip/hip_runtime.h>
#include <math.h>

// Problem constants
#define ALPHA 0.2f
#define NEG   -1e9f
constexpr int Bb = 1024;   // batch
constexpr int Nn = 100;    // nodes
constexpr int Hh = 4;      // heads
constexpr int Oo = 32;     // per-head out
constexpr int Dd = 128;    // hidden (H*O)
constexpr int K1 = 12800;  // proj GEMM1 K
constexpr int N1 = 1024;   // proj GEMM1 N
constexpr int M1 = 1024;   // proj GEMM1 M
constexpr int SK = 8;      // split-K
constexpr int KC = K1 / SK;

// ---------------------------------------------------------------------------
// Kernel 1: h[b,h,n,o] = sum_f x[b,n,f] * W[h,f,o]; fused e_src/e_dst.
// One block per (b, head). W (F x 32) staged in LDS. Each thread owns
// (n, og) = 4 consecutive o outputs -> x load amortized over 4 FMAs.
// ---------------------------------------------------------------------------
__global__ __launch_bounds__(256) void gat_h(
    const float* __restrict__ x, int F,
    const float* __restrict__ W,    // (H, F, 32) for this layer
    const float* __restrict__ av,   // (H, 64) for this layer
    float* __restrict__ h_ws, float* __restrict__ esrc, float* __restrict__ edst)
{
    __shared__ __align__(16) float Ws[128 * 32];
    __shared__ float as_[64];
    const int tid = threadIdx.x;
    const int b = blockIdx.x >> 2, hd = blockIdx.x & 3;
    const int FO = F * 32;
    for (int i = tid; i < FO; i += 256) Ws[i] = W[(size_t)hd * FO + i];
    if (tid < 64) as_[tid] = av[hd * 64 + tid];
    __syncthreads();

    const float* xb = x + (size_t)b * Nn * F;
    float* hb = h_ws + (size_t)(b * Hh + hd) * Nn * 32;
    const int ebase = (b * Hh + hd) * Nn;

    for (int it = 0; it < 4; ++it) {
        const int idx = it * 256 + tid;        // idx = n*8 + og
        const bool act = idx < Nn * 8;
        const int n = idx >> 3, og = idx & 7;
        float a0 = 0.f, a1 = 0.f, a2 = 0.f, a3 = 0.f;
        if (act) {
            const float* xr = xb + (size_t)n * F;
            const float* wp = Ws + og * 4;
            #pragma unroll 4
            for (int f = 0; f < F; ++f) {
                const float xv = xr[f];
                const float* w4 = wp + f * 32;
                a0 += xv * w4[0]; a1 += xv * w4[1];
                a2 += xv * w4[2]; a3 += xv * w4[3];
            }
            *(float4*)(hb + n * 32 + og * 4) = make_float4(a0, a1, a2, a3);
        }
        float ps = 0.f, pd = 0.f;
        if (act) {
            const int o0 = og * 4;
            ps = a0 * as_[o0] + a1 * as_[o0 + 1] + a2 * as_[o0 + 2] + a3 * as_[o0 + 3];
            pd = a0 * as_[32 + o0] + a1 * as_[32 + o0 + 1] + a2 * as_[32 + o0 + 2] + a3 * as_[32 + o0 + 3];
        }
        // reduce over og (8 lanes share one n)
        #pragma unroll
        for (int mk = 4; mk >= 1; mk >>= 1) {
            ps += __shfl_xor(ps, mk, 64);
            pd += __shfl_xor(pd, mk, 64);
        }
        if (act && og == 0) { esrc[ebase + n] = ps; edst[ebase + n] = pd; }
    }
}

// ---------------------------------------------------------------------------
// Kernel 2: masked softmax attention + PV + ELU + head-concat.
// One block per (b, head); h (100x32) staged in LDS; one wave per row n.
// All 4 waves execute exactly 25 row-iterations -> __syncthreads is uniform.
// ---------------------------------------------------------------------------
__global__ __launch_bounds__(256) void gat_attn(
    const float* __restrict__ A,
    const float* __restrict__ h_ws,
    const float* __restrict__ esrc, const float* __restrict__ edst,
    float* __restrict__ xout)
{
    __shared__ __align__(16) float hs[Nn * 32];
    __shared__ float ess[Nn], eds[Nn];
    __shared__ float watt[4][104];
    const int tid = threadIdx.x;
    const int b = blockIdx.x >> 2, hd = blockIdx.x & 3;
    {
        const float* hbp = h_ws + (size_t)(b * Hh + hd) * Nn * 32;
        for (int i = tid; i < Nn * 32; i += 256) hs[i] = hbp[i];
        if (tid < Nn) {
            ess[tid] = esrc[(b * Hh + hd) * Nn + tid];
            eds[tid] = edst[(b * Hh + hd) * Nn + tid];
        }
    }
    __syncthreads();

    const int w = tid >> 6, lane = tid & 63;
    const float* Ab = A + (size_t)b * Nn * Nn;
    float* xo = xout + (size_t)b * Nn * Dd + hd * 32;

    for (int n = w; n < Nn; n += 4) {
        const float* Ar = Ab + n * Nn;
        const float es = ess[n];
        // e values for m = lane and m = lane+64
        float e1 = es + eds[lane];
        e1 = e1 >= 0.f ? e1 : ALPHA * e1;
        float v1 = (Ar[lane] > 0.f) ? e1 : NEG;
        float v2 = -INFINITY;
        const int m2 = lane + 64;
        if (m2 < Nn) {
            float e2 = es + eds[m2];
            e2 = e2 >= 0.f ? e2 : ALPHA * e2;
            v2 = (Ar[m2] > 0.f) ? e2 : NEG;
        }
        float mx = fmaxf(v1, v2);
        #pragma unroll
        for (int s = 32; s >= 1; s >>= 1) mx = fmaxf(mx, __shfl_xor(mx, s, 64));
        const float p1 = __expf(v1 - mx);
        const float p2 = (m2 < Nn) ? __expf(v2 - mx) : 0.f;
        float sm = p1 + p2;
        #pragma unroll
        for (int s = 32; s >= 1; s >>= 1) sm += __shfl_xor(sm, s, 64);
        const float inv = 1.0f / sm;
        watt[w][lane] = p1 * inv;
        if (m2 < Nn) watt[w][m2] = p2 * inv;
        __syncthreads();

        // PV: lane = (seg, og); og*4 = 4 consecutive o, seg = m-segment (13/12)
        const int og = lane & 7, seg = lane >> 3;
        const int mstart = seg * 12 + (seg < 4 ? seg : 4);
        const int mcnt = (seg < 4) ? 13 : 12;
        float b0 = 0.f, b1 = 0.f, b2 = 0.f, b3 = 0.f;
        const float* wa = watt[w];
        for (int m = mstart; m < mstart + mcnt; ++m) {
            const float avv = wa[m];
            const float* hp = hs + m * 32 + og * 4;
            b0 += avv * hp[0]; b1 += avv * hp[1];
            b2 += avv * hp[2]; b3 += avv * hp[3];
        }
        #pragma unroll
        for (int s = 8; s <= 32; s <<= 1) {
            b0 += __shfl_xor(b0, s, 64);
            b1 += __shfl_xor(b1, s, 64);
            b2 += __shfl_xor(b2, s, 64);
            b3 += __shfl_xor(b3, s, 64);
        }
        if (seg == 0) {
            float4 r;
            r.x = b0 > 0.f ? b0 : expm1f(b0);
            r.y = b1 > 0.f ? b1 : expm1f(b1);
            r.z = b2 > 0.f ? b2 : expm1f(b2);
            r.w = b3 > 0.f ? b3 : expm1f(b3);
            *(float4*)(xo + n * Dd + og * 4) = r;
        }
        __syncthreads();
    }
}

// ---------------------------------------------------------------------------
// GEMM1 split-K: (1024 x 12800) x (12800 x 1024), fp32, 64x64 tile,
// 4x4 per-thread micro-tile, BK=16. Deterministic partials per K-slice.
// ---------------------------------------------------------------------------
__global__ __launch_bounds__(256) void gemm1(
    const float* __restrict__ Ag, const float* __restrict__ Bg,
    float* __restrict__ part)
{
    __shared__ __align__(16) float As[16][68];
    __shared__ __align__(16) float Bs[16][68];
    const int tid = threadIdx.x;
    const int n0 = blockIdx.x * 64, m0 = blockIdx.y * 64, kz = blockIdx.z;
    const int tx = tid & 15, ty = tid >> 4;
    const int ar = tid >> 2, ac = (tid & 3) << 2;
    const int br = tid >> 4, bc = (tid & 15) << 2;
    float acc[4][4] = {};

    const float* Ap = Ag + (size_t)(m0 + ar) * K1 + kz * KC + ac;
    const float* Bp = Bg + (size_t)(kz * KC + br) * N1 + n0 + bc;

    for (int t = 0; t < KC / 16; ++t) {
        const float4 a4 = *(const float4*)(Ap + t * 16);
        const float4 b4 = *(const float4*)(Bp + (size_t)t * 16 * N1);
        __syncthreads();
        As[ac + 0][ar] = a4.x; As[ac + 1][ar] = a4.y;
        As[ac + 2][ar] = a4.z; As[ac + 3][ar] = a4.w;
        *(float4*)&Bs[br][bc] = b4;
        __syncthreads();
        #pragma unroll
        for (int k = 0; k < 16; ++k) {
            const float4 a = *(const float4*)&As[k][ty * 4];
            const float4 v = *(const float4*)&Bs[k][tx * 4];
            acc[0][0] += a.x * v.x; acc[0][1] += a.x * v.y; acc[0][2] += a.x * v.z; acc[0][3] += a.x * v.w;
            acc[1][0] += a.y * v.x; acc[1][1] += a.y * v.y; acc[1][2] += a.y * v.z; acc[1][3] += a.y * v.w;
            acc[2][0] += a.z * v.x; acc[2][1] += a.z * v.y; acc[2][2] += a.z * v.z; acc[2][3] += a.z * v.w;
            acc[3][0] += a.w * v.x; acc[3][1] += a.w * v.y; acc[3][2] += a.w * v.z; acc[3][3] += a.w * v.w;
        }
    }
    float* cp = part + (size_t)kz * M1 * N1 + (size_t)(m0 + ty * 4) * N1 + n0 + tx * 4;
    #pragma unroll
    for (int i = 0; i < 4; ++i) {
        *(float4*)(cp + (size_t)i * N1) = make_float4(acc[i][0], acc[i][1], acc[i][2], acc[i][3]);
    }
}

// Reduce split-K partials + bias + BN(eval) + ReLU
__global__ __launch_bounds__(256) void bn1_reduce(
    const float* __restrict__ part, const float* __restrict__ pb1,
    const float* __restrict__ g1, const float* __restrict__ be1,
    float* __restrict__ y1)
{
    const int idx = blockIdx.x * 256 + threadIdx.x;
    float s = 0.f;
    #pragma unroll
    for (int z = 0; z < SK; ++z) s += part[(size_t)z * M1 * N1 + idx];
    const int j = idx & (N1 - 1);
    s += pb1[j];
    const float rbn = 1.0f / sqrtf(1.0f + 1e-5f);
    s = g1[j] * s * rbn + be1[j];
    y1[idx] = fmaxf(s, 0.f);
}

// GEMM2 (1024x1024)x(1024x128) + bias + BN + ReLU -> d_out
__global__ __launch_bounds__(128) void gemm2_bn(
    const float* __restrict__ y1, const float* __restrict__ W2,
    const float* __restrict__ pb2, const float* __restrict__ g2,
    const float* __restrict__ be2, float* __restrict__ out)
{
    __shared__ __align__(16) float xr[1024];
    const int tid = threadIdx.x, m = blockIdx.x;
    for (int i = tid; i < 1024; i += 128) xr[i] = y1[(size_t)m * 1024 + i];
    __syncthreads();
    float acc = 0.f;
    #pragma unroll 8
    for (int k = 0; k < 1024; ++k) acc += xr[k] * W2[k * 128 + tid];
    acc += pb2[tid];
    const float rbn = 1.0f / sqrtf(1.0f + 1e-5f);
    acc = g2[tid] * acc * rbn + be2[tid];
    out[(size_t)m * 128 + tid] = fmaxf(acc, 0.f);
}

// ---------------------------------------------------------------------------
extern "C" void kernel_launch(void* const* d_in, const int* in_sizes, int n_in,
                              void* d_out, int out_size, void* d_ws, size_t ws_size,
                              hipStream_t stream)
{
    const float* X   = (const float*)d_in[0];
    const float* A   = (const float*)d_in[1];
    const float* W0  = (const float*)d_in[2];
    const float* a0  = (const float*)d_in[3];
    const float* Wl  = (const float*)d_in[4];
    const float* al  = (const float*)d_in[5];
    const float* pW1 = (const float*)d_in[6];
    const float* pb1 = (const float*)d_in[7];
    const float* g1  = (const float*)d_in[8];
    const float* be1 = (const float*)d_in[9];
    const float* pW2 = (const float*)d_in[10];
    const float* pb2 = (const float*)d_in[11];
    const float* g2  = (const float*)d_in[12];
    const float* be2 = (const float*)d_in[13];
    float* out = (float*)d_out;

    // Workspace layout (floats). y1-partials overlay h_ws (h dead by then).
    float* ws   = (float*)d_ws;
    float* x_ws = ws;                                   // 13,107,200 (B*N*D)
    float* h_ws = x_ws + (size_t)Bb * Nn * Dd;          // 13,107,200 (B*H*N*O)
    float* es   = h_ws + (size_t)Bb * Hh * Nn * Oo;     //    409,600
    float* ed   = es + (size_t)Bb * Hh * Nn;            //    409,600
    float* y1   = ed + (size_t)Bb * Hh * Nn;            //  1,048,576
    float* part = h_ws;                                 // reuse: 8,388,608 <= 13,107,200

    // Layer 0 (F=65, input X)
    gat_h<<<dim3(Bb * Hh), 256, 0, stream>>>(X, 65, W0, a0, h_ws, es, ed);
    gat_attn<<<dim3(Bb * Hh), 256, 0, stream>>>(A, h_ws, es, ed, x_ws);
    // Layers 1..4 (F=128)
    for (int l = 1; l < 5; ++l) {
        const float* Wp = Wl + (size_t)(l - 1) * Hh * Dd * Oo;
        const float* ap = al + (size_t)(l - 1) * Hh * 2 * Oo;
        gat_h<<<dim3(Bb * Hh), 256, 0, stream>>>(x_ws, 128, Wp, ap, h_ws, es, ed);
        gat_attn<<<dim3(Bb * Hh), 256, 0, stream>>>(A, h_ws, es, ed, x_ws);
    }
    // Projection MLP
    gemm1<<<dim3(N1 / 64, M1 / 64, SK), 256, 0, stream>>>(x_ws, pW1, part);
    bn1_reduce<<<dim3((M1 * N1) / 256), 256, 0, stream>>>(part, pb1, g1, be1, y1);
    gemm2_bn<<<dim3(M1), 128, 0, stream>>>(y1, pW2, pb2, g2, be2, out);
}

// Round 2
// 1288.639 us; speedup vs baseline: 1.3849x; 1.3849x over previous
//
#include <hip/hip_runtime.h>
#include <math.h>

typedef __attribute__((ext_vector_type(8))) short short8;   // 8 bf16 (4 VGPR) MFMA A/B frag
typedef __attribute__((ext_vector_type(4))) float f32x4;    // MFMA C/D frag

constexpr int Bb = 1024, Nn = 100, Hh = 4, Oo = 32, Dd = 128;
constexpr int K1 = 12800, N1 = 1024, M1 = 1024, SK = 8, KC = K1 / SK;

// bf16 round-to-nearest-even split helpers
__device__ __forceinline__ ushort f2bf(float f) {
    uint u = __float_as_uint(f);
    return (ushort)((u + 0x7FFFu + ((u >> 16) & 1u)) >> 16);
}
__device__ __forceinline__ float bf2f(ushort h) {
    return __uint_as_float(((uint)h) << 16);
}
// swizzled byte address within a [rows][256B] LDS tile: XOR 16B-slot bits with row&7
__device__ __forceinline__ int swzb(int row, int kb) { return row * 256 + (kb ^ ((row & 7) << 4)); }

// LDS byte offsets (dynamic smem, 96000 B total, 1 block/CU)
#define OFF_XPH 0        /* x / P hi  [112][256B] bf16 */
#define OFF_XPL 28672    /* x / P lo */
#define OFF_HTH 57344    /* hT hi [32][256B] */
#define OFF_HTL 65536
#define OFF_WTH 73728    /* WT hi [32][256B] */
#define OFF_WTL 81920
#define OFF_AB  90112    /* adjacency bitmask [128][4 u32] */
#define OFF_ASV 92160    /* a-vector 64 f32 */
#define OFF_ESV 92416    /* e_src [128] f32 */
#define OFF_EDV 92928    /* e_dst [128] f32 */
#define OFF_PRT 93440    /* rowsum partials [4][128] f32 */
#define OFF_INV 95488    /* 1/rowsum [128] f32 */
#define GAT_LDS 96000

// ---------------------------------------------------------------------------
// Fused GAT layer: per (b, head) block, 512 threads (8 waves).
//   ph0 zero LDS; ph1 stage x(split-bf16,swizzled)+WT(split,transposed)+av;
//   ph2 MFMA-1 h=x*W -> hT split-bf16; ph3 es/ed sweep + A bit-pack + P-pad zero;
//   ph4 e-pass (n-in-lanes, no-max softmax, unnormalized p -> P split-bf16);
//   ph5 inv; ph6 MFMA-2 PV -> scale*elu -> global.
// ---------------------------------------------------------------------------
template<int F, int KD>
__global__ __launch_bounds__(512) void gat_fused(
    const float* __restrict__ xin,   // [B][100][F]
    const float* __restrict__ Ag,    // [B][100][100]
    const float* __restrict__ W,     // [H][F][32]
    const float* __restrict__ av,    // [H][64]
    float* __restrict__ xout)        // [B][100][128]
{
    extern __shared__ char smem[];
    char* XPH = smem + OFF_XPH;
    char* XPL = smem + OFF_XPL;
    char* HTH = smem + OFF_HTH;
    char* HTL = smem + OFF_HTL;
    char* WTH = smem + OFF_WTH;
    char* WTL = smem + OFF_WTL;
    uint*  AB  = (uint*)(smem + OFF_AB);
    float* ASV = (float*)(smem + OFF_ASV);
    float* ESV = (float*)(smem + OFF_ESV);
    float* EDV = (float*)(smem + OFF_EDV);
    float* PRT = (float*)(smem + OFF_PRT);
    float* INV = (float*)(smem + OFF_INV);

    const int tid = threadIdx.x;
    const int b = blockIdx.x >> 2, hd = blockIdx.x & 3;
    const int w = tid >> 6, lane = tid & 63;
    const int c16 = lane & 15, r16 = lane >> 4;

    // ---- ph0: zero x/P + hT + WT regions (90112 B = 11*512*16 exactly)
    {
        uint4 z = {0u, 0u, 0u, 0u};
        #pragma unroll
        for (int i = 0; i < 11; ++i)
            *(uint4*)(smem + (i * 512 + tid) * 16) = z;
    }
    __syncthreads();

    // ---- ph1: stage x (split bf16, swizzled), WT (transposed split), av
    if (F == 128) {
        const float4* xg4 = (const float4*)(xin + (size_t)b * Nn * 128);
        #pragma unroll
        for (int it = 0; it < 7; ++it) {
            int id = it * 512 + tid;            // 3200 float4-chunks
            if (id < 3200) {
                int n = id >> 5, cg = id & 31;  // 4 floats at f=4*cg
                float4 v = xg4[id];
                ushort h0 = f2bf(v.x), h1 = f2bf(v.y), h2 = f2bf(v.z), h3 = f2bf(v.w);
                ushort l0 = f2bf(v.x - bf2f(h0)), l1 = f2bf(v.y - bf2f(h1));
                ushort l2 = f2bf(v.z - bf2f(h2)), l3 = f2bf(v.w - bf2f(h3));
                uint2 uh; uh.x = (uint)h0 | ((uint)h1 << 16); uh.y = (uint)h2 | ((uint)h3 << 16);
                uint2 ul; ul.x = (uint)l0 | ((uint)l1 << 16); ul.y = (uint)l2 | ((uint)l3 << 16);
                *(uint2*)(XPH + swzb(n, 8 * cg)) = uh;
                *(uint2*)(XPL + swzb(n, 8 * cg)) = ul;
            }
        }
    } else {  // F == 65, rows only 4B-aligned: scalar path
        const float* xg = xin + (size_t)b * Nn * F;
        int n = tid >> 2, j = tid & 3;
        if (n < 100) {
            int f0 = j * 16, fend = (j == 3) ? 65 : f0 + 16;
            for (int f = f0; f < fend; ++f) {
                float v = xg[n * F + f];
                ushort hh = f2bf(v);
                ushort hl = f2bf(v - bf2f(hh));
                *(ushort*)(XPH + swzb(n, 2 * f)) = hh;
                *(ushort*)(XPL + swzb(n, 2 * f)) = hl;
            }
        }
    }
    {   // WT: W[hd][f][o] -> WT[o][f] split
        const float4* Wg4 = (const float4*)(W + (size_t)hd * F * 32);
        #pragma unroll
        for (int it = 0; it < 2; ++it) {
            int id = it * 512 + tid;            // F*8 chunks (f, o4)
            if (id < F * 8) {
                int f = id >> 3, o4 = (id & 7) * 4;
                float4 v = Wg4[id];
                ushort h0 = f2bf(v.x), l0 = f2bf(v.x - bf2f(h0));
                ushort h1 = f2bf(v.y), l1 = f2bf(v.y - bf2f(h1));
                ushort h2 = f2bf(v.z), l2 = f2bf(v.z - bf2f(h2));
                ushort h3 = f2bf(v.w), l3 = f2bf(v.w - bf2f(h3));
                *(ushort*)(WTH + swzb(o4 + 0, 2 * f)) = h0; *(ushort*)(WTL + swzb(o4 + 0, 2 * f)) = l0;
                *(ushort*)(WTH + swzb(o4 + 1, 2 * f)) = h1; *(ushort*)(WTL + swzb(o4 + 1, 2 * f)) = l1;
                *(ushort*)(WTH + swzb(o4 + 2, 2 * f)) = h2; *(ushort*)(WTL + swzb(o4 + 2, 2 * f)) = l2;
                *(ushort*)(WTH + swzb(o4 + 3, 2 * f)) = h3; *(ushort*)(WTL + swzb(o4 + 3, 2 * f)) = l3;
            }
        }
    }
    if (tid < 64) ASV[tid] = av[hd * 64 + tid];
    __syncthreads();

    // ---- ph2: MFMA-1  h = x * W  -> hT split-bf16 (rows=o, k=node)
    for (int p = w; p < 14; p += 8) {
        const int mf = p >> 1, nf = p & 1;
        const int arow = mf * 16 + c16, brow = nf * 16 + c16;
        f32x4 acc = {0.f, 0.f, 0.f, 0.f};
        #pragma unroll
        for (int d = 0; d < KD; ++d) {
            const int kb = d * 64 + r16 * 16;
            short8 ah = *(const short8*)(XPH + swzb(arow, kb));
            short8 al = *(const short8*)(XPL + swzb(arow, kb));
            short8 bh = *(const short8*)(WTH + swzb(brow, kb));
            short8 bl = *(const short8*)(WTL + swzb(brow, kb));
            acc = __builtin_amdgcn_mfma_f32_16x16x32_bf16(ah, bh, acc, 0, 0, 0);
            acc = __builtin_amdgcn_mfma_f32_16x16x32_bf16(al, bh, acc, 0, 0, 0);
            acc = __builtin_amdgcn_mfma_f32_16x16x32_bf16(ah, bl, acc, 0, 0, 0);
        }
        const int n0 = mf * 16 + r16 * 4, o = nf * 16 + c16;
        if (n0 < 100) {  // n0 multiple of 4; chunks never straddle 100
            ushort h0 = f2bf(acc[0]), l0 = f2bf(acc[0] - bf2f(h0));
            ushort h1 = f2bf(acc[1]), l1 = f2bf(acc[1] - bf2f(h1));
            ushort h2 = f2bf(acc[2]), l2 = f2bf(acc[2] - bf2f(h2));
            ushort h3 = f2bf(acc[3]), l3 = f2bf(acc[3] - bf2f(h3));
            uint2 uh; uh.x = (uint)h0 | ((uint)h1 << 16); uh.y = (uint)h2 | ((uint)h3 << 16);
            uint2 ul; ul.x = (uint)l0 | ((uint)l1 << 16); ul.y = (uint)l2 | ((uint)l3 << 16);
            *(uint2*)(HTH + swzb(o, 2 * n0)) = uh;
            *(uint2*)(HTL + swzb(o, 2 * n0)) = ul;
        }
    }
    __syncthreads();

    // ---- ph3: es/ed sweep | A bit-pack | P k-pad zero (x is dead now)
    if (tid < 100) {
        float es_ = 0.f, ed_ = 0.f;
        #pragma unroll
        for (int o = 0; o < 32; ++o) {
            float h = bf2f(*(const ushort*)(HTH + swzb(o, 2 * tid)))
                    + bf2f(*(const ushort*)(HTL + swzb(o, 2 * tid)));
            es_ += h * ASV[o];
            ed_ += h * ASV[32 + o];
        }
        ESV[tid] = es_; EDV[tid] = ed_;
    } else if (tid >= 128 && tid < 228) {
        const int r = tid - 128;
        const float4* Ar = (const float4*)(Ag + ((size_t)b * Nn + r) * Nn);
        uint bw0 = 0, bw1 = 0, bw2 = 0, bw3 = 0;
        #pragma unroll
        for (int cc = 0; cc < 25; ++cc) {
            float4 v = Ar[cc];
            uint b4 = (v.x > 0.f ? 1u : 0u) | (v.y > 0.f ? 2u : 0u)
                    | (v.z > 0.f ? 4u : 0u) | (v.w > 0.f ? 8u : 0u);
            int sh = (cc * 4) & 31;
            if (cc < 8) bw0 |= b4 << sh; else if (cc < 16) bw1 |= b4 << sh;
            else if (cc < 24) bw2 |= b4 << sh; else bw3 |= b4 << sh;
        }
        uint4 u; u.x = bw0; u.y = bw1; u.z = bw2; u.w = bw3;
        *(uint4*)(AB + r * 4) = u;
    } else if (tid >= 256) {
        const int t = tid - 256;
        #pragma unroll
        for (int i = 0; i < 7; ++i) {
            int id = i * 256 + t;               // 112 rows * 16 slots
            int row = id >> 4, s = id & 15;
            if (s < 14) {                        // bytes 200..255 = m 100..127
                int byte = 200 + 4 * s;
                *(uint*)(XPH + swzb(row, byte)) = 0u;
                *(uint*)(XPL + swzb(row, byte)) = 0u;
            }
        }
    }
    __syncthreads();

    // ---- ph4: e-pass. lane=n, wave splits m-range; no-max softmax (e bounded)
    {
        const int q = w & 3, nset = w >> 2;
        const int n = nset * 64 + lane;
        const bool val = n < 100;
        const int m0 = q * 28, mlen = (q < 3) ? 28 : 16;
        float esn = 0.f;
        uint a0 = 0, a1 = 0, a2 = 0, a3 = 0;
        if (val) {
            esn = ESV[n];
            uint4 ab = *(const uint4*)(AB + n * 4);
            a0 = ab.x; a1 = ab.y; a2 = ab.z; a3 = ab.w;
        }
        float rsum = 0.f;
        for (int mc = 0; mc < mlen / 4; ++mc) {
            uint whx = 0, why = 0, wlx = 0, wly = 0;
            #pragma unroll
            for (int j = 0; j < 4; ++j) {
                int m = m0 + mc * 4 + j;
                float e = esn + EDV[m];
                e = e > 0.f ? e : 0.2f * e;      // LeakyReLU
                int wsel = m >> 5;
                uint wrd = wsel == 0 ? a0 : (wsel == 1 ? a1 : (wsel == 2 ? a2 : a3));
                float p = ((wrd >> (m & 31)) & 1u) ? __expf(e) : 0.f;
                rsum += p;
                ushort pb = f2bf(p);
                ushort pl = f2bf(p - bf2f(pb));
                if (j == 0)      { whx |= pb;              wlx |= pl; }
                else if (j == 1) { whx |= (uint)pb << 16;  wlx |= (uint)pl << 16; }
                else if (j == 2) { why |= pb;              wly |= pl; }
                else             { why |= (uint)pb << 16;  wly |= (uint)pl << 16; }
            }
            if (val) {
                int byte = 2 * (m0 + mc * 4);
                uint2 uh; uh.x = whx; uh.y = why;
                uint2 ul; ul.x = wlx; ul.y = wly;
                *(uint2*)(XPH + swzb(n, byte)) = uh;   // P overlays x
                *(uint2*)(XPL + swzb(n, byte)) = ul;
            }
        }
        if (val) PRT[q * 128 + n] = rsum;
    }
    __syncthreads();

    // ---- ph5: inverse row sums
    if (tid < 100)
        INV[tid] = 1.f / (PRT[tid] + PRT[128 + tid] + PRT[256 + tid] + PRT[384 + tid]);
    __syncthreads();

    // ---- ph6: MFMA-2  out = elu( (P*h) * inv ) -> global
    for (int p = w; p < 14; p += 8) {
        const int mf = p >> 1, nf = p & 1;
        const int arow = mf * 16 + c16, brow = nf * 16 + c16;
        f32x4 acc = {0.f, 0.f, 0.f, 0.f};
        #pragma unroll
        for (int d = 0; d < 4; ++d) {
            const int kb = d * 64 + r16 * 16;
            short8 ah = *(const short8*)(XPH + swzb(arow, kb));
            short8 al = *(const short8*)(XPL + swzb(arow, kb));
            short8 bh = *(const short8*)(HTH + swzb(brow, kb));
            short8 bl = *(const short8*)(HTL + swzb(brow, kb));
            acc = __builtin_amdgcn_mfma_f32_16x16x32_bf16(ah, bh, acc, 0, 0, 0);
            acc = __builtin_amdgcn_mfma_f32_16x16x32_bf16(al, bh, acc, 0, 0, 0);
            acc = __builtin_amdgcn_mfma_f32_16x16x32_bf16(ah, bl, acc, 0, 0, 0);
        }
        const int n0 = mf * 16 + r16 * 4, o = nf * 16 + c16;
        #pragma unroll
        for (int r = 0; r < 4; ++r) {
            int n = n0 + r;
            if (n < 100) {
                float v = acc[r] * INV[n];
                v = v > 0.f ? v : expm1f(v);     // ELU
                xout[((size_t)b * Nn + n) * Dd + hd * 32 + o] = v;
            }
        }
    }
}

// ---------------------------------------------------------------------------
// GEMM1 split-K fp32 (unchanged this round): (1024x12800)x(12800x1024)
// ---------------------------------------------------------------------------
__global__ __launch_bounds__(256) void gemm1(
    const float* __restrict__ Ag, const float* __restrict__ Bg,
    float* __restrict__ part)
{
    __shared__ __align__(16) float As[16][68];
    __shared__ __align__(16) float Bs[16][68];
    const int tid = threadIdx.x;
    const int n0 = blockIdx.x * 64, m0 = blockIdx.y * 64, kz = blockIdx.z;
    const int tx = tid & 15, ty = tid >> 4;
    const int ar = tid >> 2, ac = (tid & 3) << 2;
    const int br = tid >> 4, bc = (tid & 15) << 2;
    float acc[4][4] = {};

    const float* Ap = Ag + (size_t)(m0 + ar) * K1 + kz * KC + ac;
    const float* Bp = Bg + (size_t)(kz * KC + br) * N1 + n0 + bc;

    for (int t = 0; t < KC / 16; ++t) {
        const float4 a4 = *(const float4*)(Ap + t * 16);
        const float4 b4 = *(const float4*)(Bp + (size_t)t * 16 * N1);
        __syncthreads();
        As[ac + 0][ar] = a4.x; As[ac + 1][ar] = a4.y;
        As[ac + 2][ar] = a4.z; As[ac + 3][ar] = a4.w;
        *(float4*)&Bs[br][bc] = b4;
        __syncthreads();
        #pragma unroll
        for (int k = 0; k < 16; ++k) {
            const float4 a = *(const float4*)&As[k][ty * 4];
            const float4 v = *(const float4*)&Bs[k][tx * 4];
            acc[0][0] += a.x * v.x; acc[0][1] += a.x * v.y; acc[0][2] += a.x * v.z; acc[0][3] += a.x * v.w;
            acc[1][0] += a.y * v.x; acc[1][1] += a.y * v.y; acc[1][2] += a.y * v.z; acc[1][3] += a.y * v.w;
            acc[2][0] += a.z * v.x; acc[2][1] += a.z * v.y; acc[2][2] += a.z * v.z; acc[2][3] += a.z * v.w;
            acc[3][0] += a.w * v.x; acc[3][1] += a.w * v.y; acc[3][2] += a.w * v.z; acc[3][3] += a.w * v.w;
        }
    }
    float* cp = part + (size_t)kz * M1 * N1 + (size_t)(m0 + ty * 4) * N1 + n0 + tx * 4;
    #pragma unroll
    for (int i = 0; i < 4; ++i)
        *(float4*)(cp + (size_t)i * N1) = make_float4(acc[i][0], acc[i][1], acc[i][2], acc[i][3]);
}

__global__ __launch_bounds__(256) void bn1_reduce(
    const float* __restrict__ part, const float* __restrict__ pb1,
    const float* __restrict__ g1, const float* __restrict__ be1,
    float* __restrict__ y1)
{
    const int idx = blockIdx.x * 256 + threadIdx.x;
    float s = 0.f;
    #pragma unroll
    for (int z = 0; z < SK; ++z) s += part[(size_t)z * M1 * N1 + idx];
    const int j = idx & (N1 - 1);
    s += pb1[j];
    const float rbn = 1.0f / sqrtf(1.0f + 1e-5f);
    s = g1[j] * s * rbn + be1[j];
    y1[idx] = fmaxf(s, 0.f);
}

__global__ __launch_bounds__(128) void gemm2_bn(
    const float* __restrict__ y1, const float* __restrict__ W2,
    const float* __restrict__ pb2, const float* __restrict__ g2,
    const float* __restrict__ be2, float* __restrict__ out)
{
    __shared__ __align__(16) float xr[1024];
    const int tid = threadIdx.x, m = blockIdx.x;
    for (int i = tid; i < 1024; i += 128) xr[i] = y1[(size_t)m * 1024 + i];
    __syncthreads();
    float acc = 0.f;
    #pragma unroll 8
    for (int k = 0; k < 1024; ++k) acc += xr[k] * W2[k * 128 + tid];
    acc += pb2[tid];
    const float rbn = 1.0f / sqrtf(1.0f + 1e-5f);
    acc = g2[tid] * acc * rbn + be2[tid];
    out[(size_t)m * 128 + tid] = fmaxf(acc, 0.f);
}

// ---------------------------------------------------------------------------
extern "C" void kernel_launch(void* const* d_in, const int* in_sizes, int n_in,
                              void* d_out, int out_size, void* d_ws, size_t ws_size,
                              hipStream_t stream)
{
    const float* X   = (const float*)d_in[0];
    const float* A   = (const float*)d_in[1];
    const float* W0  = (const float*)d_in[2];
    const float* a0  = (const float*)d_in[3];
    const float* Wl  = (const float*)d_in[4];
    const float* al  = (const float*)d_in[5];
    const float* pW1 = (const float*)d_in[6];
    const float* pb1 = (const float*)d_in[7];
    const float* g1  = (const float*)d_in[8];
    const float* be1 = (const float*)d_in[9];
    const float* pW2 = (const float*)d_in[10];
    const float* pb2 = (const float*)d_in[11];
    const float* g2  = (const float*)d_in[12];
    const float* be2 = (const float*)d_in[13];
    float* out = (float*)d_out;

    // ws: xa(13.1M) | xb(13.1M, reused as gemm1 partials) | y1(1.05M) = 109 MB
    float* ws = (float*)d_ws;
    float* xa = ws;
    float* xb = xa + (size_t)Bb * Nn * Dd;
    float* y1 = xb + (size_t)Bb * Nn * Dd;
    float* part = xb;

    (void)hipFuncSetAttribute(reinterpret_cast<const void*>(gat_fused<65, 3>),
                              hipFuncAttributeMaxDynamicSharedMemorySize, GAT_LDS);
    (void)hipFuncSetAttribute(reinterpret_cast<const void*>(gat_fused<128, 4>),
                              hipFuncAttributeMaxDynamicSharedMemorySize, GAT_LDS);

    gat_fused<65, 3><<<dim3(Bb * Hh), 512, GAT_LDS, stream>>>(X, A, W0, a0, xa);
    const float* src = xa; float* dst = xb;
    for (int l = 1; l < 5; ++l) {
        gat_fused<128, 4><<<dim3(Bb * Hh), 512, GAT_LDS, stream>>>(
            src, A, Wl + (size_t)(l - 1) * Hh * Dd * Oo, al + (size_t)(l - 1) * Hh * 2 * Oo, dst);
        float* t = (float*)src; src = dst; dst = t;
    }
    // after 4 swaps src == xa holds the final GAT output; xb is free for partials
    gemm1<<<dim3(N1 / 64, M1 / 64, SK), 256, 0, stream>>>(src, pW1, part);
    bn1_reduce<<<dim3((M1 * N1) / 256), 256, 0, stream>>>(part, pb1, g1, be1, y1);
    gemm2_bn<<<dim3(M1), 128, 0, stream>>>(y1, pW2, pb2, g2, be2, out);
}

// Round 3
// 1061.134 us; speedup vs baseline: 1.6818x; 1.2144x over previous
//
#include <hip/hip_runtime.h>
#include <math.h>

typedef __attribute__((ext_vector_type(8))) short short8;   // 8 bf16 (4 VGPR) MFMA A/B frag
typedef __attribute__((ext_vector_type(4))) float f32x4;    // MFMA C/D frag

constexpr int Bb = 1024, Nn = 100, Hh = 4, Oo = 32, Dd = 128;
constexpr int K1 = 12800, N1 = 1024, M1 = 1024, SK = 8;

// bf16 round-to-nearest-even split helpers
__device__ __forceinline__ ushort f2bf(float f) {
    uint u = __float_as_uint(f);
    return (ushort)((u + 0x7FFFu + ((u >> 16) & 1u)) >> 16);
}
__device__ __forceinline__ float bf2f(ushort h) {
    return __uint_as_float(((uint)h) << 16);
}
// swizzled byte address within a [rows][256B] LDS tile: XOR 16B-slot bits with row&7
__device__ __forceinline__ int swzb(int row, int kb) { return row * 256 + (kb ^ ((row & 7) << 4)); }

// LDS byte offsets for GAT (dynamic smem, 96000 B total)
#define OFF_XPH 0        /* x / P hi  [112][256B] bf16 */
#define OFF_XPL 28672    /* x / P lo */
#define OFF_HTH 57344    /* hT hi [32][256B] */
#define OFF_HTL 65536
#define OFF_WTH 73728    /* WT hi [32][256B] */
#define OFF_WTL 81920
#define OFF_AB  90112    /* adjacency bitmask [128][4 u32] */
#define OFF_ASV 92160    /* a-vector 64 f32 */
#define OFF_ESV 92416    /* e_src [128] f32 */
#define OFF_EDV 92928    /* e_dst [128] f32 */
#define OFF_PRT 93440    /* rowsum partials [4][128] f32 */
#define OFF_INV 95488    /* 1/rowsum [128] f32 */
#define GAT_LDS 96000

// ---------------------------------------------------------------------------
// Fused GAT layer (unchanged from round 2)
// ---------------------------------------------------------------------------
template<int F, int KD>
__global__ __launch_bounds__(512) void gat_fused(
    const float* __restrict__ xin,   // [B][100][F]
    const float* __restrict__ Ag,    // [B][100][100]
    const float* __restrict__ W,     // [H][F][32]
    const float* __restrict__ av,    // [H][64]
    float* __restrict__ xout)        // [B][100][128]
{
    extern __shared__ char smem[];
    char* XPH = smem + OFF_XPH;
    char* XPL = smem + OFF_XPL;
    char* HTH = smem + OFF_HTH;
    char* HTL = smem + OFF_HTL;
    char* WTH = smem + OFF_WTH;
    char* WTL = smem + OFF_WTL;
    uint*  AB  = (uint*)(smem + OFF_AB);
    float* ASV = (float*)(smem + OFF_ASV);
    float* ESV = (float*)(smem + OFF_ESV);
    float* EDV = (float*)(smem + OFF_EDV);
    float* PRT = (float*)(smem + OFF_PRT);
    float* INV = (float*)(smem + OFF_INV);

    const int tid = threadIdx.x;
    const int b = blockIdx.x >> 2, hd = blockIdx.x & 3;
    const int w = tid >> 6, lane = tid & 63;
    const int c16 = lane & 15, r16 = lane >> 4;

    // ---- ph0: zero x/P + hT + WT regions (90112 B = 11*512*16 exactly)
    {
        uint4 z = {0u, 0u, 0u, 0u};
        #pragma unroll
        for (int i = 0; i < 11; ++i)
            *(uint4*)(smem + (i * 512 + tid) * 16) = z;
    }
    __syncthreads();

    // ---- ph1: stage x (split bf16, swizzled), WT (transposed split), av
    if (F == 128) {
        const float4* xg4 = (const float4*)(xin + (size_t)b * Nn * 128);
        #pragma unroll
        for (int it = 0; it < 7; ++it) {
            int id = it * 512 + tid;            // 3200 float4-chunks
            if (id < 3200) {
                int n = id >> 5, cg = id & 31;  // 4 floats at f=4*cg
                float4 v = xg4[id];
                ushort h0 = f2bf(v.x), h1 = f2bf(v.y), h2 = f2bf(v.z), h3 = f2bf(v.w);
                ushort l0 = f2bf(v.x - bf2f(h0)), l1 = f2bf(v.y - bf2f(h1));
                ushort l2 = f2bf(v.z - bf2f(h2)), l3 = f2bf(v.w - bf2f(h3));
                uint2 uh; uh.x = (uint)h0 | ((uint)h1 << 16); uh.y = (uint)h2 | ((uint)h3 << 16);
                uint2 ul; ul.x = (uint)l0 | ((uint)l1 << 16); ul.y = (uint)l2 | ((uint)l3 << 16);
                *(uint2*)(XPH + swzb(n, 8 * cg)) = uh;
                *(uint2*)(XPL + swzb(n, 8 * cg)) = ul;
            }
        }
    } else {  // F == 65, rows only 4B-aligned: scalar path
        const float* xg = xin + (size_t)b * Nn * F;
        int n = tid >> 2, j = tid & 3;
        if (n < 100) {
            int f0 = j * 16, fend = (j == 3) ? 65 : f0 + 16;
            for (int f = f0; f < fend; ++f) {
                float v = xg[n * F + f];
                ushort hh = f2bf(v);
                ushort hl = f2bf(v - bf2f(hh));
                *(ushort*)(XPH + swzb(n, 2 * f)) = hh;
                *(ushort*)(XPL + swzb(n, 2 * f)) = hl;
            }
        }
    }
    {   // WT: W[hd][f][o] -> WT[o][f] split
        const float4* Wg4 = (const float4*)(W + (size_t)hd * F * 32);
        #pragma unroll
        for (int it = 0; it < 2; ++it) {
            int id = it * 512 + tid;            // F*8 chunks (f, o4)
            if (id < F * 8) {
                int f = id >> 3, o4 = (id & 7) * 4;
                float4 v = Wg4[id];
                ushort h0 = f2bf(v.x), l0 = f2bf(v.x - bf2f(h0));
                ushort h1 = f2bf(v.y), l1 = f2bf(v.y - bf2f(h1));
                ushort h2 = f2bf(v.z), l2 = f2bf(v.z - bf2f(h2));
                ushort h3 = f2bf(v.w), l3 = f2bf(v.w - bf2f(h3));
                *(ushort*)(WTH + swzb(o4 + 0, 2 * f)) = h0; *(ushort*)(WTL + swzb(o4 + 0, 2 * f)) = l0;
                *(ushort*)(WTH + swzb(o4 + 1, 2 * f)) = h1; *(ushort*)(WTL + swzb(o4 + 1, 2 * f)) = l1;
                *(ushort*)(WTH + swzb(o4 + 2, 2 * f)) = h2; *(ushort*)(WTL + swzb(o4 + 2, 2 * f)) = l2;
                *(ushort*)(WTH + swzb(o4 + 3, 2 * f)) = h3; *(ushort*)(WTL + swzb(o4 + 3, 2 * f)) = l3;
            }
        }
    }
    if (tid < 64) ASV[tid] = av[hd * 64 + tid];
    __syncthreads();

    // ---- ph2: MFMA-1  h = x * W  -> hT split-bf16 (rows=o, k=node)
    for (int p = w; p < 14; p += 8) {
        const int mf = p >> 1, nf = p & 1;
        const int arow = mf * 16 + c16, brow = nf * 16 + c16;
        f32x4 acc = {0.f, 0.f, 0.f, 0.f};
        #pragma unroll
        for (int d = 0; d < KD; ++d) {
            const int kb = d * 64 + r16 * 16;
            short8 ah = *(const short8*)(XPH + swzb(arow, kb));
            short8 al = *(const short8*)(XPL + swzb(arow, kb));
            short8 bh = *(const short8*)(WTH + swzb(brow, kb));
            short8 bl = *(const short8*)(WTL + swzb(brow, kb));
            acc = __builtin_amdgcn_mfma_f32_16x16x32_bf16(ah, bh, acc, 0, 0, 0);
            acc = __builtin_amdgcn_mfma_f32_16x16x32_bf16(al, bh, acc, 0, 0, 0);
            acc = __builtin_amdgcn_mfma_f32_16x16x32_bf16(ah, bl, acc, 0, 0, 0);
        }
        const int n0 = mf * 16 + r16 * 4, o = nf * 16 + c16;
        if (n0 < 100) {  // n0 multiple of 4; chunks never straddle 100
            ushort h0 = f2bf(acc[0]), l0 = f2bf(acc[0] - bf2f(h0));
            ushort h1 = f2bf(acc[1]), l1 = f2bf(acc[1] - bf2f(h1));
            ushort h2 = f2bf(acc[2]), l2 = f2bf(acc[2] - bf2f(h2));
            ushort h3 = f2bf(acc[3]), l3 = f2bf(acc[3] - bf2f(h3));
            uint2 uh; uh.x = (uint)h0 | ((uint)h1 << 16); uh.y = (uint)h2 | ((uint)h3 << 16);
            uint2 ul; ul.x = (uint)l0 | ((uint)l1 << 16); ul.y = (uint)l2 | ((uint)l3 << 16);
            *(uint2*)(HTH + swzb(o, 2 * n0)) = uh;
            *(uint2*)(HTL + swzb(o, 2 * n0)) = ul;
        }
    }
    __syncthreads();

    // ---- ph3: es/ed sweep | A bit-pack | P k-pad zero (x is dead now)
    if (tid < 100) {
        float es_ = 0.f, ed_ = 0.f;
        #pragma unroll
        for (int o = 0; o < 32; ++o) {
            float h = bf2f(*(const ushort*)(HTH + swzb(o, 2 * tid)))
                    + bf2f(*(const ushort*)(HTL + swzb(o, 2 * tid)));
            es_ += h * ASV[o];
            ed_ += h * ASV[32 + o];
        }
        ESV[tid] = es_; EDV[tid] = ed_;
    } else if (tid >= 128 && tid < 228) {
        const int r = tid - 128;
        const float4* Ar = (const float4*)(Ag + ((size_t)b * Nn + r) * Nn);
        uint bw0 = 0, bw1 = 0, bw2 = 0, bw3 = 0;
        #pragma unroll
        for (int cc = 0; cc < 25; ++cc) {
            float4 v = Ar[cc];
            uint b4 = (v.x > 0.f ? 1u : 0u) | (v.y > 0.f ? 2u : 0u)
                    | (v.z > 0.f ? 4u : 0u) | (v.w > 0.f ? 8u : 0u);
            int sh = (cc * 4) & 31;
            if (cc < 8) bw0 |= b4 << sh; else if (cc < 16) bw1 |= b4 << sh;
            else if (cc < 24) bw2 |= b4 << sh; else bw3 |= b4 << sh;
        }
        uint4 u; u.x = bw0; u.y = bw1; u.z = bw2; u.w = bw3;
        *(uint4*)(AB + r * 4) = u;
    } else if (tid >= 256) {
        const int t = tid - 256;
        #pragma unroll
        for (int i = 0; i < 7; ++i) {
            int id = i * 256 + t;               // 112 rows * 16 slots
            int row = id >> 4, s = id & 15;
            if (s < 14) {                        // bytes 200..255 = m 100..127
                int byte = 200 + 4 * s;
                *(uint*)(XPH + swzb(row, byte)) = 0u;
                *(uint*)(XPL + swzb(row, byte)) = 0u;
            }
        }
    }
    __syncthreads();

    // ---- ph4: e-pass. lane=n, wave splits m-range; no-max softmax (e bounded)
    {
        const int q = w & 3, nset = w >> 2;
        const int n = nset * 64 + lane;
        const bool val = n < 100;
        const int m0 = q * 28, mlen = (q < 3) ? 28 : 16;
        float esn = 0.f;
        uint a0 = 0, a1 = 0, a2 = 0, a3 = 0;
        if (val) {
            esn = ESV[n];
            uint4 ab = *(const uint4*)(AB + n * 4);
            a0 = ab.x; a1 = ab.y; a2 = ab.z; a3 = ab.w;
        }
        float rsum = 0.f;
        for (int mc = 0; mc < mlen / 4; ++mc) {
            uint whx = 0, why = 0, wlx = 0, wly = 0;
            #pragma unroll
            for (int j = 0; j < 4; ++j) {
                int m = m0 + mc * 4 + j;
                float e = esn + EDV[m];
                e = e > 0.f ? e : 0.2f * e;      // LeakyReLU
                int wsel = m >> 5;
                uint wrd = wsel == 0 ? a0 : (wsel == 1 ? a1 : (wsel == 2 ? a2 : a3));
                float p = ((wrd >> (m & 31)) & 1u) ? __expf(e) : 0.f;
                rsum += p;
                ushort pb = f2bf(p);
                ushort pl = f2bf(p - bf2f(pb));
                if (j == 0)      { whx |= pb;              wlx |= pl; }
                else if (j == 1) { whx |= (uint)pb << 16;  wlx |= (uint)pl << 16; }
                else if (j == 2) { why |= pb;              wly |= pl; }
                else             { why |= (uint)pb << 16;  wly |= (uint)pl << 16; }
            }
            if (val) {
                int byte = 2 * (m0 + mc * 4);
                uint2 uh; uh.x = whx; uh.y = why;
                uint2 ul; ul.x = wlx; ul.y = wly;
                *(uint2*)(XPH + swzb(n, byte)) = uh;   // P overlays x
                *(uint2*)(XPL + swzb(n, byte)) = ul;
            }
        }
        if (val) PRT[q * 128 + n] = rsum;
    }
    __syncthreads();

    // ---- ph5: inverse row sums
    if (tid < 100)
        INV[tid] = 1.f / (PRT[tid] + PRT[128 + tid] + PRT[256 + tid] + PRT[384 + tid]);
    __syncthreads();

    // ---- ph6: MFMA-2  out = elu( (P*h) * inv ) -> global
    for (int p = w; p < 14; p += 8) {
        const int mf = p >> 1, nf = p & 1;
        const int arow = mf * 16 + c16, brow = nf * 16 + c16;
        f32x4 acc = {0.f, 0.f, 0.f, 0.f};
        #pragma unroll
        for (int d = 0; d < 4; ++d) {
            const int kb = d * 64 + r16 * 16;
            short8 ah = *(const short8*)(XPH + swzb(arow, kb));
            short8 al = *(const short8*)(XPL + swzb(arow, kb));
            short8 bh = *(const short8*)(HTH + swzb(brow, kb));
            short8 bl = *(const short8*)(HTL + swzb(brow, kb));
            acc = __builtin_amdgcn_mfma_f32_16x16x32_bf16(ah, bh, acc, 0, 0, 0);
            acc = __builtin_amdgcn_mfma_f32_16x16x32_bf16(al, bh, acc, 0, 0, 0);
            acc = __builtin_amdgcn_mfma_f32_16x16x32_bf16(ah, bl, acc, 0, 0, 0);
        }
        const int n0 = mf * 16 + r16 * 4, o = nf * 16 + c16;
        #pragma unroll
        for (int r = 0; r < 4; ++r) {
            int n = n0 + r;
            if (n < 100) {
                float v = acc[r] * INV[n];
                v = v > 0.f ? v : expm1f(v);     // ELU
                xout[((size_t)b * Nn + n) * Dd + hd * 32 + o] = v;
            }
        }
    }
}

// ---------------------------------------------------------------------------
// GEMM1 split-bf16 MFMA: (1024 x 12800) x (12800 x 1024) fp32-equivalent.
// 128m x 256n tile, BK=64, SK=8, 512 thr (8 waves as 2m x 4n of 64x64).
// Truncation hi/lo split (hi = upper 16 bits; lo compensates exactly).
// A LDS [128][144B]; B LDS [256][144B] with slot-XOR on (n>>3)&1.
// XCD swizzle: 8 consecutive same-XCD slots share one (n,z) B-panel (L2).
// ---------------------------------------------------------------------------
#define G1_LDS 110592
__device__ __forceinline__ int aofs(int r, int kb) { return r * 144 + kb; }
__device__ __forceinline__ int bofs(int n, int kb) { return n * 144 + (kb ^ (((n >> 3) & 1) << 4)); }

__global__ __launch_bounds__(512, 2) void gemm1_mfma(
    const float* __restrict__ Ag, const float* __restrict__ Bg,
    float* __restrict__ part)
{
    extern __shared__ char sm[];
    char* AH = sm;             // [128][144]
    char* AL = sm + 18432;
    char* BH = sm + 36864;     // [256][144]
    char* BL = sm + 73728;

    const int tid = threadIdx.x;
    // XCD-aware decode: same-XCD consecutive slots share (n,z) group
    const int pb = blockIdx.x;
    const int xcd = pb & 7, slot = pb >> 3;          // slot 0..31
    const int group = xcd * 4 + (slot >> 3);         // 0..31 -> (nb, z)
    const int mb = slot & 7;
    const int nb = group >> 3, z = group & 7;
    const int m0 = mb * 128, n0 = nb * 256;
    const int k0 = z * 1600;

    const int w = tid >> 6, lane = tid & 63;
    const int wn = w & 3, wm = w >> 2;               // wave tile 64m x 64n
    const int c16 = lane & 15, r16 = lane >> 4;

    // staging roles
    const int ra = tid >> 2, kq = tid & 3;           // A: row, 16-k quarter
    const int bn = tid >> 1, bkh = tid & 1;          // B: col n, 32-k half

    const float* Aptr = Ag + (size_t)(m0 + ra) * K1 + k0 + kq * 16;
    const float* Bptr = Bg + (size_t)(k0 + bkh * 32) * N1 + n0 + bn;

    f32x4 acc[4][4];
    #pragma unroll
    for (int i = 0; i < 4; ++i)
        #pragma unroll
        for (int j = 0; j < 4; ++j) acc[i][j] = (f32x4){0.f, 0.f, 0.f, 0.f};

    float a_reg[16];
    float b_reg[32];
    // prologue: load iter 0
    #pragma unroll
    for (int q = 0; q < 4; ++q) *(float4*)&a_reg[q * 4] = *(const float4*)(Aptr + q * 4);
    #pragma unroll
    for (int j = 0; j < 32; ++j) b_reg[j] = Bptr[(size_t)j * N1];

    for (int it = 0; it < 25; ++it) {
        __syncthreads();   // previous iter's MFMA reads done -> LDS writable
        // ---- convert + write regs -> LDS (truncation split, perm pack)
        {
            uint hi[8], lo[8];
            #pragma unroll
            for (int i = 0; i < 8; ++i) {
                uint u0 = __float_as_uint(a_reg[2 * i]);
                uint u1 = __float_as_uint(a_reg[2 * i + 1]);
                float l0 = a_reg[2 * i]     - __uint_as_float(u0 & 0xFFFF0000u);
                float l1 = a_reg[2 * i + 1] - __uint_as_float(u1 & 0xFFFF0000u);
                hi[i] = __builtin_amdgcn_perm(u1, u0, 0x07060302u);
                lo[i] = __builtin_amdgcn_perm(__float_as_uint(l1), __float_as_uint(l0), 0x07060302u);
            }
            const int ab = aofs(ra, kq * 32);
            *(uint4*)(AH + ab)      = make_uint4(hi[0], hi[1], hi[2], hi[3]);
            *(uint4*)(AH + ab + 16) = make_uint4(hi[4], hi[5], hi[6], hi[7]);
            *(uint4*)(AL + ab)      = make_uint4(lo[0], lo[1], lo[2], lo[3]);
            *(uint4*)(AL + ab + 16) = make_uint4(lo[4], lo[5], lo[6], lo[7]);
        }
        {
            uint hi[16], lo[16];
            #pragma unroll
            for (int i = 0; i < 16; ++i) {
                uint u0 = __float_as_uint(b_reg[2 * i]);
                uint u1 = __float_as_uint(b_reg[2 * i + 1]);
                float l0 = b_reg[2 * i]     - __uint_as_float(u0 & 0xFFFF0000u);
                float l1 = b_reg[2 * i + 1] - __uint_as_float(u1 & 0xFFFF0000u);
                hi[i] = __builtin_amdgcn_perm(u1, u0, 0x07060302u);
                lo[i] = __builtin_amdgcn_perm(__float_as_uint(l1), __float_as_uint(l0), 0x07060302u);
            }
            #pragma unroll
            for (int q = 0; q < 4; ++q) {
                const int bb = bofs(bn, bkh * 64 + q * 16);
                *(uint4*)(BH + bb) = make_uint4(hi[4 * q], hi[4 * q + 1], hi[4 * q + 2], hi[4 * q + 3]);
                *(uint4*)(BL + bb) = make_uint4(lo[4 * q], lo[4 * q + 1], lo[4 * q + 2], lo[4 * q + 3]);
            }
        }
        __syncthreads();   // LDS tile ready

        // ---- prefetch next iter into regs (hidden under MFMA)
        if (it < 24) {
            Aptr += 64;
            Bptr += (size_t)64 * N1;
            #pragma unroll
            for (int q = 0; q < 4; ++q) *(float4*)&a_reg[q * 4] = *(const float4*)(Aptr + q * 4);
            #pragma unroll
            for (int j = 0; j < 32; ++j) b_reg[j] = Bptr[(size_t)j * N1];
        }

        // ---- MFMA sweep over two 32-k steps
        #pragma unroll
        for (int ks = 0; ks < 2; ++ks) {
            const int kb = ks * 64 + r16 * 16;
            short8 bh[4], bl[4];
            #pragma unroll
            for (int nf = 0; nf < 4; ++nf) {
                const int nr = wn * 64 + nf * 16 + c16;
                bh[nf] = *(const short8*)(BH + bofs(nr, kb));
                bl[nf] = *(const short8*)(BL + bofs(nr, kb));
            }
            #pragma unroll
            for (int mf = 0; mf < 4; ++mf) {
                const int ar = wm * 64 + mf * 16 + c16;
                short8 ah = *(const short8*)(AH + aofs(ar, kb));
                short8 al = *(const short8*)(AL + aofs(ar, kb));
                #pragma unroll
                for (int nf = 0; nf < 4; ++nf) {
                    acc[mf][nf] = __builtin_amdgcn_mfma_f32_16x16x32_bf16(ah, bh[nf], acc[mf][nf], 0, 0, 0);
                    acc[mf][nf] = __builtin_amdgcn_mfma_f32_16x16x32_bf16(al, bh[nf], acc[mf][nf], 0, 0, 0);
                    acc[mf][nf] = __builtin_amdgcn_mfma_f32_16x16x32_bf16(ah, bl[nf], acc[mf][nf], 0, 0, 0);
                }
            }
        }
    }

    // ---- epilogue: store fp32 partials
    float* pz = part + (size_t)z * M1 * N1;
    #pragma unroll
    for (int mf = 0; mf < 4; ++mf) {
        const int m = m0 + wm * 64 + mf * 16 + r16 * 4;
        #pragma unroll
        for (int nf = 0; nf < 4; ++nf) {
            const int n = n0 + wn * 64 + nf * 16 + c16;
            #pragma unroll
            for (int r = 0; r < 4; ++r)
                pz[(size_t)(m + r) * N1 + n] = acc[mf][nf][r];
        }
    }
}

// Reduce split-K partials + bias + BN(eval) + ReLU
__global__ __launch_bounds__(256) void bn1_reduce(
    const float* __restrict__ part, const float* __restrict__ pb1,
    const float* __restrict__ g1, const float* __restrict__ be1,
    float* __restrict__ y1)
{
    const int idx = blockIdx.x * 256 + threadIdx.x;
    float s = 0.f;
    #pragma unroll
    for (int z = 0; z < SK; ++z) s += part[(size_t)z * M1 * N1 + idx];
    const int j = idx & (N1 - 1);
    s += pb1[j];
    const float rbn = 1.0f / sqrtf(1.0f + 1e-5f);
    s = g1[j] * s * rbn + be1[j];
    y1[idx] = fmaxf(s, 0.f);
}

// GEMM2 (1024x1024)x(1024x128) + bias + BN + ReLU -> d_out
__global__ __launch_bounds__(128) void gemm2_bn(
    const float* __restrict__ y1, const float* __restrict__ W2,
    const float* __restrict__ pb2, const float* __restrict__ g2,
    const float* __restrict__ be2, float* __restrict__ out)
{
    __shared__ __align__(16) float xr[1024];
    const int tid = threadIdx.x, m = blockIdx.x;
    for (int i = tid; i < 1024; i += 128) xr[i] = y1[(size_t)m * 1024 + i];
    __syncthreads();
    float acc = 0.f;
    #pragma unroll 8
    for (int k = 0; k < 1024; ++k) acc += xr[k] * W2[k * 128 + tid];
    acc += pb2[tid];
    const float rbn = 1.0f / sqrtf(1.0f + 1e-5f);
    acc = g2[tid] * acc * rbn + be2[tid];
    out[(size_t)m * 128 + tid] = fmaxf(acc, 0.f);
}

// ---------------------------------------------------------------------------
extern "C" void kernel_launch(void* const* d_in, const int* in_sizes, int n_in,
                              void* d_out, int out_size, void* d_ws, size_t ws_size,
                              hipStream_t stream)
{
    const float* X   = (const float*)d_in[0];
    const float* A   = (const float*)d_in[1];
    const float* W0  = (const float*)d_in[2];
    const float* a0  = (const float*)d_in[3];
    const float* Wl  = (const float*)d_in[4];
    const float* al  = (const float*)d_in[5];
    const float* pW1 = (const float*)d_in[6];
    const float* pb1 = (const float*)d_in[7];
    const float* g1  = (const float*)d_in[8];
    const float* be1 = (const float*)d_in[9];
    const float* pW2 = (const float*)d_in[10];
    const float* pb2 = (const float*)d_in[11];
    const float* g2  = (const float*)d_in[12];
    const float* be2 = (const float*)d_in[13];
    float* out = (float*)d_out;

    // ws: xa(52.4MB) | xb(52.4MB, reused as gemm1 partials 32MB) | y1(4.2MB)
    float* ws = (float*)d_ws;
    float* xa = ws;
    float* xb = xa + (size_t)Bb * Nn * Dd;
    float* y1 = xb + (size_t)Bb * Nn * Dd;
    float* part = xb;

    (void)hipFuncSetAttribute(reinterpret_cast<const void*>(gat_fused<65, 3>),
                              hipFuncAttributeMaxDynamicSharedMemorySize, GAT_LDS);
    (void)hipFuncSetAttribute(reinterpret_cast<const void*>(gat_fused<128, 4>),
                              hipFuncAttributeMaxDynamicSharedMemorySize, GAT_LDS);
    (void)hipFuncSetAttribute(reinterpret_cast<const void*>(gemm1_mfma),
                              hipFuncAttributeMaxDynamicSharedMemorySize, G1_LDS);

    gat_fused<65, 3><<<dim3(Bb * Hh), 512, GAT_LDS, stream>>>(X, A, W0, a0, xa);
    const float* src = xa; float* dst = xb;
    for (int l = 1; l < 5; ++l) {
        gat_fused<128, 4><<<dim3(Bb * Hh), 512, GAT_LDS, stream>>>(
            src, A, Wl + (size_t)(l - 1) * Hh * Dd * Oo, al + (size_t)(l - 1) * Hh * 2 * Oo, dst);
        float* t = (float*)src; src = dst; dst = t;
    }
    // after 4 swaps src == xa holds the final GAT output; xb free for partials
    gemm1_mfma<<<dim3(256), 512, G1_LDS, stream>>>(src, pW1, part);
    bn1_reduce<<<dim3((M1 * N1) / 256), 256, 0, stream>>>(part, pb1, g1, be1, y1);
    gemm2_bn<<<dim3(M1), 128, 0, stream>>>(y1, pW2, pb2, g2, be2, out);
}

// Round 5
// 622.829 us; speedup vs baseline: 2.8653x; 1.7037x over previous
//
#include <hip/hip_runtime.h>
#include <math.h>

typedef __attribute__((ext_vector_type(8))) short short8;   // 8 bf16 (4 VGPR) MFMA A/B frag
typedef __attribute__((ext_vector_type(4))) float f32x4;    // MFMA C/D frag
typedef __attribute__((ext_vector_type(4))) uint  uint4v;

constexpr int Bb = 1024, Nn = 100, Hh = 4, Oo = 32, Dd = 128;
constexpr int K1 = 12800, N1 = 1024, M1 = 1024, SK = 8;

// bf16 round-to-nearest-even helpers
__device__ __forceinline__ ushort f2bf(float f) {
    uint u = __float_as_uint(f);
    return (ushort)((u + 0x7FFFu + ((u >> 16) & 1u)) >> 16);
}
__device__ __forceinline__ float bf2f(ushort h) {
    return __uint_as_float(((uint)h) << 16);
}
__device__ __forceinline__ short8 mk8(uint a, uint b, uint c, uint d) {
    uint4v v = {a, b, c, d};
    return __builtin_bit_cast(short8, v);
}
// swizzles within [rows][256B] LDS tiles
__device__ __forceinline__ int swzb(int row, int kb)  { return row * 256 + (kb ^ ((row & 7) << 4)); }   // HT/WT

// GAT LDS layout (dynamic, 67072 B -> 2 blocks/CU)
#define OFF_P   0        /* P bf16 hi (pass A) / lo (pass B) [112][256B] */
#define OFF_HTH 28672    /* hT hi [32][256B] */
#define OFF_HTL 36864
#define OFF_WTH 45056    /* WT hi [32][256B] */
#define OFF_WTL 53248
#define OFF_AB  61440    /* adjacency bitmask [100][4 u32] (pad 112) */
#define OFF_ASV 63232    /* a-vector 64 f32 */
#define OFF_ESV 63488    /* e_src [128] f32 */
#define OFF_EDV 64000    /* e_dst [128] f32 */
#define OFF_PRT 64512    /* rowsum partials [4][128] f32 */
#define OFF_INV 66560    /* 1/rowsum [128] f32 */
#define GAT_LDS 67072

// ---------------------------------------------------------------------------
// pack_A: adjacency -> 128-bit masks, once per b (not per head).
// ---------------------------------------------------------------------------
__global__ __launch_bounds__(256) void pack_A(const float* __restrict__ A, uint* __restrict__ AW)
{
    const int b = blockIdx.x;
    const float4* Ab = (const float4*)(A + (size_t)b * 10000);
    for (int t = threadIdx.x; t < 400; t += 256) {
        const int row = t >> 2, word = t & 3;
        uint bits = 0;
        if (word < 3) {
            #pragma unroll
            for (int j = 0; j < 8; ++j) {
                float4 v = Ab[row * 25 + word * 8 + j];
                uint b4 = (v.x > 0.f ? 1u : 0u) | (v.y > 0.f ? 2u : 0u)
                        | (v.z > 0.f ? 4u : 0u) | (v.w > 0.f ? 8u : 0u);
                bits |= b4 << (j * 4);
            }
        } else {
            float4 v = Ab[row * 25 + 24];   // cols 96..99; 100..127 stay 0
            bits = (v.x > 0.f ? 1u : 0u) | (v.y > 0.f ? 2u : 0u)
                 | (v.z > 0.f ? 4u : 0u) | (v.w > 0.f ? 8u : 0u);
        }
        AW[(size_t)b * 400 + t] = bits;
    }
}

// ---------------------------------------------------------------------------
// Fused GAT layer v2.1: per (b, head) block, 512 thr, 2 blocks/CU.
//   x streamed global->regs; P stored split hi/lo via TWO passes through the
//   same LDS region (hi kept through ph6a, lo rewritten from registers);
//   es/ed from MFMA-1 accumulators; adjacency pre-packed.
// ---------------------------------------------------------------------------
template<int F, int KD>
__global__ __launch_bounds__(512, 4) void gat_fused(
    const float* __restrict__ xin,   // [B][100][F]
    const uint*  __restrict__ AW,    // [B][100][4] packed adjacency
    const float* __restrict__ W,     // [H][F][32]
    const float* __restrict__ av,    // [H][64]
    float* __restrict__ xout)        // [B][100][128]
{
    extern __shared__ char smem[];
    char*  Pb  = smem + OFF_P;
    char*  HTH = smem + OFF_HTH;
    char*  HTL = smem + OFF_HTL;
    char*  WTH = smem + OFF_WTH;
    char*  WTL = smem + OFF_WTL;
    uint*  ABu = (uint*)(smem + OFF_AB);
    float* ASV = (float*)(smem + OFF_ASV);
    float* ESV = (float*)(smem + OFF_ESV);
    float* EDV = (float*)(smem + OFF_EDV);
    float* PRT = (float*)(smem + OFF_PRT);
    float* INV = (float*)(smem + OFF_INV);

    const int tid = threadIdx.x;
    // XCD-grouped swizzle: 4 head-blocks of one b land on one XCD, adjacent slots
    const int task = (blockIdx.x & 7) * 512 + (blockIdx.x >> 3);
    const int b = task >> 2, hd = task & 3;
    const int w = tid >> 6, lane = tid & 63;
    const int c16 = lane & 15, r16 = lane >> 4;

    const float* xg = xin + (size_t)b * Nn * F;

    if (F == 65) {   // zero WT for k-padding (f 65..95)
        uint4 z = make_uint4(0, 0, 0, 0);
        #pragma unroll
        for (int i = 0; i < 2; ++i)
            *(uint4*)(smem + OFF_WTH + (i * 512 + tid) * 16) = z;
        __syncthreads();
    }

    // ---- prefetch x fragments (F=128 path) before the staging barrier
    const int nA = (w * 16 + c16 < 100) ? (w * 16 + c16) : 99;
    float4 xpre[8];
    if (F == 128 && w < 7) {
        #pragma unroll
        for (int d = 0; d < 4; ++d) {
            const float* px = xg + (size_t)nA * 128 + d * 32 + r16 * 8;
            xpre[2 * d]     = *(const float4*)(px);
            xpre[2 * d + 1] = *(const float4*)(px + 4);
        }
    }

    // ---- ph1: stage WT (RNE hi/lo, transposed), ASV, AB copy, tail zeroing
    {
        const float4* Wg4 = (const float4*)(W + (size_t)hd * F * 32);
        #pragma unroll
        for (int it = 0; it < 2; ++it) {
            int id = it * 512 + tid;            // F*8 chunks (f, o4)
            if (id < F * 8) {
                int f = id >> 3, o4 = (id & 7) * 4;
                float4 v = Wg4[id];
                ushort h0 = f2bf(v.x), l0 = f2bf(v.x - bf2f(h0));
                ushort h1 = f2bf(v.y), l1 = f2bf(v.y - bf2f(h1));
                ushort h2 = f2bf(v.z), l2 = f2bf(v.z - bf2f(h2));
                ushort h3 = f2bf(v.w), l3 = f2bf(v.w - bf2f(h3));
                *(ushort*)(WTH + swzb(o4 + 0, 2 * f)) = h0; *(ushort*)(WTL + swzb(o4 + 0, 2 * f)) = l0;
                *(ushort*)(WTH + swzb(o4 + 1, 2 * f)) = h1; *(ushort*)(WTL + swzb(o4 + 1, 2 * f)) = l1;
                *(ushort*)(WTH + swzb(o4 + 2, 2 * f)) = h2; *(ushort*)(WTL + swzb(o4 + 2, 2 * f)) = l2;
                *(ushort*)(WTH + swzb(o4 + 3, 2 * f)) = h3; *(ushort*)(WTL + swzb(o4 + 3, 2 * f)) = l3;
            }
        }
    }
    if (tid < 64) ASV[tid] = av[hd * 64 + tid];
    {
        int idA = tid - 64;
        if (idA >= 0 && idA < 400) ABu[idA] = AW[(size_t)b * 400 + idA];
    }
    if (tid < 400) {    // zero P logical bytes 192..255 (m 96..127) rows 0..99
        const int row = tid >> 2, slot = 12 + (tid & 3);
        *(uint4*)(Pb + row * 256 + ((slot * 16) ^ ((row & 15) << 4))) = make_uint4(0, 0, 0, 0);
    }
    if (tid < 256) {    // zero hT logical bytes 192..255 (cols 96..127; 96..99 rewritten in ph2)
        char* base = (tid & 128) ? HTL : HTH;
        const int rr = (tid >> 2) & 31, sl = 12 + (tid & 3);
        *(uint4*)(base + swzb(rr, sl * 16)) = make_uint4(0, 0, 0, 0);
    }
    if (tid >= 464 && tid < 492) { ESV[tid - 364] = 0.f; EDV[tid - 364] = 0.f; }  // idx 100..127
    __syncthreads();

    // ---- ph2: MFMA-1 h = x*W (wave w owns rows w*16..+15, both o-halves)
    if (w < 7) {
        f32x4 acc0 = {0.f, 0.f, 0.f, 0.f}, acc1 = {0.f, 0.f, 0.f, 0.f};
        #pragma unroll
        for (int d = 0; d < KD; ++d) {
            float xv[8];
            if (F == 128) {
                float4 v0 = xpre[2 * d], v1 = xpre[2 * d + 1];
                xv[0] = v0.x; xv[1] = v0.y; xv[2] = v0.z; xv[3] = v0.w;
                xv[4] = v1.x; xv[5] = v1.y; xv[6] = v1.z; xv[7] = v1.w;
            } else {
                const int f0 = d * 32 + r16 * 8;
                #pragma unroll
                for (int j = 0; j < 8; ++j) {
                    int f = f0 + j;
                    xv[j] = (f < 65) ? xg[(size_t)nA * 65 + f] : 0.f;
                }
            }
            uint hu[4], lu[4];
            #pragma unroll
            for (int i = 0; i < 4; ++i) {
                uint u0 = __float_as_uint(xv[2 * i]);
                uint u1 = __float_as_uint(xv[2 * i + 1]);
                float l0 = xv[2 * i]     - __uint_as_float(u0 & 0xFFFF0000u);
                float l1 = xv[2 * i + 1] - __uint_as_float(u1 & 0xFFFF0000u);
                hu[i] = __builtin_amdgcn_perm(u1, u0, 0x07060302u);
                lu[i] = __builtin_amdgcn_perm(__float_as_uint(l1), __float_as_uint(l0), 0x07060302u);
            }
            short8 ah = mk8(hu[0], hu[1], hu[2], hu[3]);
            short8 al = mk8(lu[0], lu[1], lu[2], lu[3]);
            const int kb = d * 64 + r16 * 16;
            short8 bh0 = *(const short8*)(WTH + swzb(c16, kb));
            short8 bl0 = *(const short8*)(WTL + swzb(c16, kb));
            short8 bh1 = *(const short8*)(WTH + swzb(16 + c16, kb));
            short8 bl1 = *(const short8*)(WTL + swzb(16 + c16, kb));
            acc0 = __builtin_amdgcn_mfma_f32_16x16x32_bf16(ah, bh0, acc0, 0, 0, 0);
            acc0 = __builtin_amdgcn_mfma_f32_16x16x32_bf16(al, bh0, acc0, 0, 0, 0);
            acc0 = __builtin_amdgcn_mfma_f32_16x16x32_bf16(ah, bl0, acc0, 0, 0, 0);
            acc1 = __builtin_amdgcn_mfma_f32_16x16x32_bf16(ah, bh1, acc1, 0, 0, 0);
            acc1 = __builtin_amdgcn_mfma_f32_16x16x32_bf16(al, bh1, acc1, 0, 0, 0);
            acc1 = __builtin_amdgcn_mfma_f32_16x16x32_bf16(ah, bl1, acc1, 0, 0, 0);
        }
        const int n0 = w * 16 + r16 * 4;
        if (n0 < 100) {   // hT split write: rows o, cols n0..n0+3 (all <100)
            ushort h0 = f2bf(acc0[0]), l0 = f2bf(acc0[0] - bf2f(h0));
            ushort h1 = f2bf(acc0[1]), l1 = f2bf(acc0[1] - bf2f(h1));
            ushort h2 = f2bf(acc0[2]), l2 = f2bf(acc0[2] - bf2f(h2));
            ushort h3 = f2bf(acc0[3]), l3 = f2bf(acc0[3] - bf2f(h3));
            uint2 uh; uh.x = (uint)h0 | ((uint)h1 << 16); uh.y = (uint)h2 | ((uint)h3 << 16);
            uint2 ul; ul.x = (uint)l0 | ((uint)l1 << 16); ul.y = (uint)l2 | ((uint)l3 << 16);
            *(uint2*)(HTH + swzb(c16, 2 * n0)) = uh;
            *(uint2*)(HTL + swzb(c16, 2 * n0)) = ul;
            h0 = f2bf(acc1[0]); l0 = f2bf(acc1[0] - bf2f(h0));
            h1 = f2bf(acc1[1]); l1 = f2bf(acc1[1] - bf2f(h1));
            h2 = f2bf(acc1[2]); l2 = f2bf(acc1[2] - bf2f(h2));
            h3 = f2bf(acc1[3]); l3 = f2bf(acc1[3] - bf2f(h3));
            uh.x = (uint)h0 | ((uint)h1 << 16); uh.y = (uint)h2 | ((uint)h3 << 16);
            ul.x = (uint)l0 | ((uint)l1 << 16); ul.y = (uint)l2 | ((uint)l3 << 16);
            *(uint2*)(HTH + swzb(16 + c16, 2 * n0)) = uh;
            *(uint2*)(HTL + swzb(16 + c16, 2 * n0)) = ul;
        }
        // es/ed: reduce acc*a over 32 o's (both halves pre-summed, 16-lane xor)
        const float as0 = ASV[c16], as1 = ASV[16 + c16];
        const float ad0 = ASV[32 + c16], ad1 = ASV[48 + c16];
        #pragma unroll
        for (int r = 0; r < 4; ++r) {
            float vs = acc0[r] * as0 + acc1[r] * as1;
            float vd = acc0[r] * ad0 + acc1[r] * ad1;
            #pragma unroll
            for (int mk = 1; mk <= 8; mk <<= 1) {
                vs += __shfl_xor(vs, mk, 64);
                vd += __shfl_xor(vd, mk, 64);
            }
            if (c16 == 0 && n0 + r < 100) { ESV[n0 + r] = vs; EDV[n0 + r] = vd; }
        }
    }
    __syncthreads();

    // ---- ph4: e-pass (uniform 7 chunks; m>=100 -> p=0). Keep p in registers.
    const int q4 = w & 3, nset4 = w >> 2;
    const int n4 = nset4 * 64 + lane;
    const bool val4 = n4 < 100;
    const int m0q = q4 * 28;
    float pv[28];
    {
        float esn = 0.f;
        uint a0 = 0, a1 = 0, a2 = 0, a3 = 0;
        if (val4) {
            esn = ESV[n4];
            uint4 ab = *(const uint4*)(ABu + n4 * 4);
            a0 = ab.x; a1 = ab.y; a2 = ab.z; a3 = ab.w;
        }
        float rsum = 0.f;
        #pragma unroll
        for (int mc = 0; mc < 7; ++mc) {
            uint wh0 = 0, wh1 = 0;
            #pragma unroll
            for (int j = 0; j < 4; ++j) {
                int m = m0q + mc * 4 + j;        // < 112; EDV[>=100] zeroed
                float e = esn + EDV[m];
                e = e > 0.f ? e : 0.2f * e;      // LeakyReLU
                int wsel = m >> 5;
                uint wrd = wsel == 0 ? a0 : (wsel == 1 ? a1 : (wsel == 2 ? a2 : a3));
                float p = ((wrd >> (m & 31)) & 1u) ? __expf(e) : 0.f;
                pv[mc * 4 + j] = p;
                rsum += p;
                ushort pb = f2bf(p);
                if (j == 0)      wh0 |= pb;
                else if (j == 1) wh0 |= (uint)pb << 16;
                else if (j == 2) wh1 |= pb;
                else             wh1 |= (uint)pb << 16;
            }
            if (val4) {
                uint2 uw; uw.x = wh0; uw.y = wh1;
                const int byte = 2 * m0q + 8 * mc;
                *(uint2*)(Pb + n4 * 256 + (byte ^ ((n4 & 15) << 4))) = uw;
            }
        }
        if (val4) PRT[q4 * 128 + n4] = rsum;
    }
    __syncthreads();

    // ---- ph5: inverse row sums
    if (tid < 100)
        INV[tid] = 1.f / (PRT[tid] + PRT[128 + tid] + PRT[256 + tid] + PRT[384 + tid]);
    __syncthreads();

    // ---- ph6a: acc += P_hi * (h_hi + h_lo)
    f32x4 acc0 = {0.f, 0.f, 0.f, 0.f}, acc1 = {0.f, 0.f, 0.f, 0.f};
    if (w < 7) {
        #pragma unroll
        for (int d = 0; d < 4; ++d) {
            const int kb = d * 64 + r16 * 16;
            short8 pa  = *(const short8*)(Pb + nA * 256 + (kb ^ ((nA & 15) << 4)));
            short8 bh0 = *(const short8*)(HTH + swzb(c16, kb));
            short8 bl0 = *(const short8*)(HTL + swzb(c16, kb));
            short8 bh1 = *(const short8*)(HTH + swzb(16 + c16, kb));
            short8 bl1 = *(const short8*)(HTL + swzb(16 + c16, kb));
            acc0 = __builtin_amdgcn_mfma_f32_16x16x32_bf16(pa, bh0, acc0, 0, 0, 0);
            acc0 = __builtin_amdgcn_mfma_f32_16x16x32_bf16(pa, bl0, acc0, 0, 0, 0);
            acc1 = __builtin_amdgcn_mfma_f32_16x16x32_bf16(pa, bh1, acc1, 0, 0, 0);
            acc1 = __builtin_amdgcn_mfma_f32_16x16x32_bf16(pa, bl1, acc1, 0, 0, 0);
        }
    }
    __syncthreads();

    // ---- ph4b: rewrite P region with lo residuals (from registers)
    {
        #pragma unroll
        for (int mc = 0; mc < 7; ++mc) {
            uint wl0 = 0, wl1 = 0;
            #pragma unroll
            for (int j = 0; j < 4; ++j) {
                float p = pv[mc * 4 + j];
                float lo = p - bf2f(f2bf(p));
                ushort lb = f2bf(lo);
                if (j == 0)      wl0 |= lb;
                else if (j == 1) wl0 |= (uint)lb << 16;
                else if (j == 2) wl1 |= lb;
                else             wl1 |= (uint)lb << 16;
            }
            if (val4) {
                uint2 uw; uw.x = wl0; uw.y = wl1;
                const int byte = 2 * m0q + 8 * mc;
                *(uint2*)(Pb + n4 * 256 + (byte ^ ((n4 & 15) << 4))) = uw;
            }
        }
    }
    __syncthreads();

    // ---- ph6b: acc += P_lo * h_hi; epilogue elu((acc)*inv) -> global
    if (w < 7) {
        #pragma unroll
        for (int d = 0; d < 4; ++d) {
            const int kb = d * 64 + r16 * 16;
            short8 pl  = *(const short8*)(Pb + nA * 256 + (kb ^ ((nA & 15) << 4)));
            short8 bh0 = *(const short8*)(HTH + swzb(c16, kb));
            short8 bh1 = *(const short8*)(HTH + swzb(16 + c16, kb));
            acc0 = __builtin_amdgcn_mfma_f32_16x16x32_bf16(pl, bh0, acc0, 0, 0, 0);
            acc1 = __builtin_amdgcn_mfma_f32_16x16x32_bf16(pl, bh1, acc1, 0, 0, 0);
        }
        const int n0 = w * 16 + r16 * 4;
        float* xo = xout + (size_t)b * Nn * Dd + hd * 32;
        #pragma unroll
        for (int r = 0; r < 4; ++r) {
            int n = n0 + r;
            if (n < 100) {
                float inv = INV[n];
                float v0 = acc0[r] * inv; v0 = v0 > 0.f ? v0 : expm1f(v0);
                float v1 = acc1[r] * inv; v1 = v1 > 0.f ? v1 : expm1f(v1);
                xo[(size_t)n * Dd + c16] = v0;
                xo[(size_t)n * Dd + 16 + c16] = v1;
            }
        }
    }
}

// ---------------------------------------------------------------------------
// GEMM1 split-bf16 MFMA (unchanged from round 3)
// ---------------------------------------------------------------------------
#define G1_LDS 110592
__device__ __forceinline__ int aofs(int r, int kb) { return r * 144 + kb; }
__device__ __forceinline__ int bofs(int n, int kb) { return n * 144 + (kb ^ (((n >> 3) & 1) << 4)); }

__global__ __launch_bounds__(512, 2) void gemm1_mfma(
    const float* __restrict__ Ag, const float* __restrict__ Bg,
    float* __restrict__ part)
{
    extern __shared__ char sm[];
    char* AH = sm;             // [128][144]
    char* AL = sm + 18432;
    char* BH = sm + 36864;     // [256][144]
    char* BL = sm + 73728;

    const int tid = threadIdx.x;
    const int pb = blockIdx.x;
    const int xcd = pb & 7, slot = pb >> 3;
    const int group = xcd * 4 + (slot >> 3);
    const int mb = slot & 7;
    const int nb = group >> 3, z = group & 7;
    const int m0 = mb * 128, n0 = nb * 256;
    const int k0 = z * 1600;

    const int w = tid >> 6, lane = tid & 63;
    const int wn = w & 3, wm = w >> 2;
    const int c16 = lane & 15, r16 = lane >> 4;

    const int ra = tid >> 2, kq = tid & 3;
    const int bn = tid >> 1, bkh = tid & 1;

    const float* Aptr = Ag + (size_t)(m0 + ra) * K1 + k0 + kq * 16;
    const float* Bptr = Bg + (size_t)(k0 + bkh * 32) * N1 + n0 + bn;

    f32x4 acc[4][4];
    #pragma unroll
    for (int i = 0; i < 4; ++i)
        #pragma unroll
        for (int j = 0; j < 4; ++j) acc[i][j] = (f32x4){0.f, 0.f, 0.f, 0.f};

    float a_reg[16];
    float b_reg[32];
    #pragma unroll
    for (int q = 0; q < 4; ++q) *(float4*)&a_reg[q * 4] = *(const float4*)(Aptr + q * 4);
    #pragma unroll
    for (int j = 0; j < 32; ++j) b_reg[j] = Bptr[(size_t)j * N1];

    for (int it = 0; it < 25; ++it) {
        __syncthreads();
        {
            uint hi[8], lo[8];
            #pragma unroll
            for (int i = 0; i < 8; ++i) {
                uint u0 = __float_as_uint(a_reg[2 * i]);
                uint u1 = __float_as_uint(a_reg[2 * i + 1]);
                float l0 = a_reg[2 * i]     - __uint_as_float(u0 & 0xFFFF0000u);
                float l1 = a_reg[2 * i + 1] - __uint_as_float(u1 & 0xFFFF0000u);
                hi[i] = __builtin_amdgcn_perm(u1, u0, 0x07060302u);
                lo[i] = __builtin_amdgcn_perm(__float_as_uint(l1), __float_as_uint(l0), 0x07060302u);
            }
            const int ab = aofs(ra, kq * 32);
            *(uint4*)(AH + ab)      = make_uint4(hi[0], hi[1], hi[2], hi[3]);
            *(uint4*)(AH + ab + 16) = make_uint4(hi[4], hi[5], hi[6], hi[7]);
            *(uint4*)(AL + ab)      = make_uint4(lo[0], lo[1], lo[2], lo[3]);
            *(uint4*)(AL + ab + 16) = make_uint4(lo[4], lo[5], lo[6], lo[7]);
        }
        {
            uint hi[16], lo[16];
            #pragma unroll
            for (int i = 0; i < 16; ++i) {
                uint u0 = __float_as_uint(b_reg[2 * i]);
                uint u1 = __float_as_uint(b_reg[2 * i + 1]);
                float l0 = b_reg[2 * i]     - __uint_as_float(u0 & 0xFFFF0000u);
                float l1 = b_reg[2 * i + 1] - __uint_as_float(u1 & 0xFFFF0000u);
                hi[i] = __builtin_amdgcn_perm(u1, u0, 0x07060302u);
                lo[i] = __builtin_amdgcn_perm(__float_as_uint(l1), __float_as_uint(l0), 0x07060302u);
            }
            #pragma unroll
            for (int q = 0; q < 4; ++q) {
                const int bb = bofs(bn, bkh * 64 + q * 16);
                *(uint4*)(BH + bb) = make_uint4(hi[4 * q], hi[4 * q + 1], hi[4 * q + 2], hi[4 * q + 3]);
                *(uint4*)(BL + bb) = make_uint4(lo[4 * q], lo[4 * q + 1], lo[4 * q + 2], lo[4 * q + 3]);
            }
        }
        __syncthreads();

        if (it < 24) {
            Aptr += 64;
            Bptr += (size_t)64 * N1;
            #pragma unroll
            for (int q = 0; q < 4; ++q) *(float4*)&a_reg[q * 4] = *(const float4*)(Aptr + q * 4);
            #pragma unroll
            for (int j = 0; j < 32; ++j) b_reg[j] = Bptr[(size_t)j * N1];
        }

        #pragma unroll
        for (int ks = 0; ks < 2; ++ks) {
            const int kb = ks * 64 + r16 * 16;
            short8 bh[4], bl[4];
            #pragma unroll
            for (int nf = 0; nf < 4; ++nf) {
                const int nr = wn * 64 + nf * 16 + c16;
                bh[nf] = *(const short8*)(BH + bofs(nr, kb));
                bl[nf] = *(const short8*)(BL + bofs(nr, kb));
            }
            #pragma unroll
            for (int mf = 0; mf < 4; ++mf) {
                const int ar = wm * 64 + mf * 16 + c16;
                short8 ah = *(const short8*)(AH + aofs(ar, kb));
                short8 al = *(const short8*)(AL + aofs(ar, kb));
                #pragma unroll
                for (int nf = 0; nf < 4; ++nf) {
                    acc[mf][nf] = __builtin_amdgcn_mfma_f32_16x16x32_bf16(ah, bh[nf], acc[mf][nf], 0, 0, 0);
                    acc[mf][nf] = __builtin_amdgcn_mfma_f32_16x16x32_bf16(al, bh[nf], acc[mf][nf], 0, 0, 0);
                    acc[mf][nf] = __builtin_amdgcn_mfma_f32_16x16x32_bf16(ah, bl[nf], acc[mf][nf], 0, 0, 0);
                }
            }
        }
    }

    float* pz = part + (size_t)z * M1 * N1;
    #pragma unroll
    for (int mf = 0; mf < 4; ++mf) {
        const int m = m0 + wm * 64 + mf * 16 + r16 * 4;
        #pragma unroll
        for (int nf = 0; nf < 4; ++nf) {
            const int n = n0 + wn * 64 + nf * 16 + c16;
            #pragma unroll
            for (int r = 0; r < 4; ++r)
                pz[(size_t)(m + r) * N1 + n] = acc[mf][nf][r];
        }
    }
}

// Reduce split-K partials + bias + BN(eval) + ReLU
__global__ __launch_bounds__(256) void bn1_reduce(
    const float* __restrict__ part, const float* __restrict__ pb1,
    const float* __restrict__ g1, const float* __restrict__ be1,
    float* __restrict__ y1)
{
    const int idx = blockIdx.x * 256 + threadIdx.x;
    float s = 0.f;
    #pragma unroll
    for (int z = 0; z < SK; ++z) s += part[(size_t)z * M1 * N1 + idx];
    const int j = idx & (N1 - 1);
    s += pb1[j];
    const float rbn = 1.0f / sqrtf(1.0f + 1e-5f);
    s = g1[j] * s * rbn + be1[j];
    y1[idx] = fmaxf(s, 0.f);
}

// GEMM2 (1024x1024)x(1024x128) + bias + BN + ReLU -> d_out
__global__ __launch_bounds__(128) void gemm2_bn(
    const float* __restrict__ y1, const float* __restrict__ W2,
    const float* __restrict__ pb2, const float* __restrict__ g2,
    const float* __restrict__ be2, float* __restrict__ out)
{
    __shared__ __align__(16) float xr[1024];
    const int tid = threadIdx.x, m = blockIdx.x;
    for (int i = tid; i < 1024; i += 128) xr[i] = y1[(size_t)m * 1024 + i];
    __syncthreads();
    float acc = 0.f;
    #pragma unroll 8
    for (int k = 0; k < 1024; ++k) acc += xr[k] * W2[k * 128 + tid];
    acc += pb2[tid];
    const float rbn = 1.0f / sqrtf(1.0f + 1e-5f);
    acc = g2[tid] * acc * rbn + be2[tid];
    out[(size_t)m * 128 + tid] = fmaxf(acc, 0.f);
}

// ---------------------------------------------------------------------------
extern "C" void kernel_launch(void* const* d_in, const int* in_sizes, int n_in,
                              void* d_out, int out_size, void* d_ws, size_t ws_size,
                              hipStream_t stream)
{
    const float* X   = (const float*)d_in[0];
    const float* A   = (const float*)d_in[1];
    const float* W0  = (const float*)d_in[2];
    const float* a0  = (const float*)d_in[3];
    const float* Wl  = (const float*)d_in[4];
    const float* al  = (const float*)d_in[5];
    const float* pW1 = (const float*)d_in[6];
    const float* pb1 = (const float*)d_in[7];
    const float* g1  = (const float*)d_in[8];
    const float* be1 = (const float*)d_in[9];
    const float* pW2 = (const float*)d_in[10];
    const float* pb2 = (const float*)d_in[11];
    const float* g2  = (const float*)d_in[12];
    const float* be2 = (const float*)d_in[13];
    float* out = (float*)d_out;

    // ws: xa(52.4MB) | xb(52.4MB, reused as gemm1 partials) | y1(4.2MB, AW overlay)
    float* ws = (float*)d_ws;
    float* xa = ws;
    float* xb = xa + (size_t)Bb * Nn * Dd;
    float* y1 = xb + (size_t)Bb * Nn * Dd;
    float* part = xb;
    uint*  AW = (uint*)y1;          // packed adjacency, dead before bn1 writes y1

    (void)hipFuncSetAttribute(reinterpret_cast<const void*>(gat_fused<65, 3>),
                              hipFuncAttributeMaxDynamicSharedMemorySize, GAT_LDS);
    (void)hipFuncSetAttribute(reinterpret_cast<const void*>(gat_fused<128, 4>),
                              hipFuncAttributeMaxDynamicSharedMemorySize, GAT_LDS);
    (void)hipFuncSetAttribute(reinterpret_cast<const void*>(gemm1_mfma),
                              hipFuncAttributeMaxDynamicSharedMemorySize, G1_LDS);

    pack_A<<<dim3(Bb), 256, 0, stream>>>(A, AW);
    gat_fused<65, 3><<<dim3(Bb * Hh), 512, GAT_LDS, stream>>>(X, AW, W0, a0, xa);
    const float* src = xa; float* dst = xb;
    for (int l = 1; l < 5; ++l) {
        gat_fused<128, 4><<<dim3(Bb * Hh), 512, GAT_LDS, stream>>>(
            src, AW, Wl + (size_t)(l - 1) * Hh * Dd * Oo, al + (size_t)(l - 1) * Hh * 2 * Oo, dst);
        float* t = (float*)src; src = dst; dst = t;
    }
    gemm1_mfma<<<dim3(256), 512, G1_LDS, stream>>>(src, pW1, part);
    bn1_reduce<<<dim3((M1 * N1) / 256), 256, 0, stream>>>(part, pb1, g1, be1, y1);
    gemm2_bn<<<dim3(M1), 128, 0, stream>>>(y1, pW2, pb2, g2, be2, out);
}

// Round 9
// 585.620 us; speedup vs baseline: 3.0474x; 1.0635x over previous
//
#include <hip/hip_runtime.h>
#include <math.h>

typedef __attribute__((ext_vector_type(8))) short short8;   // 8 bf16 (4 VGPR) MFMA A/B frag
typedef __attribute__((ext_vector_type(4))) float f32x4;    // MFMA C/D frag
typedef __attribute__((ext_vector_type(4))) uint  uint4v;

constexpr int Bb = 1024, Nn = 100, Hh = 4, Oo = 32, Dd = 128;
constexpr int K1 = 12800, N1 = 1024, M1 = 1024, SK = 8;

// bf16 round-to-nearest-even helpers
__device__ __forceinline__ ushort f2bf(float f) {
    uint u = __float_as_uint(f);
    return (ushort)((u + 0x7FFFu + ((u >> 16) & 1u)) >> 16);
}
__device__ __forceinline__ float bf2f(ushort h) {
    return __uint_as_float(((uint)h) << 16);
}
__device__ __forceinline__ short8 mk8(uint a, uint b, uint c, uint d) {
    uint4v v = {a, b, c, d};
    return __builtin_bit_cast(short8, v);
}
// swizzle within [rows][256B] LDS tiles: XOR 16B-slot bits with row&7
__device__ __forceinline__ int swzb(int row, int kb)  { return row * 256 + (kb ^ ((row & 7) << 4)); }

// GAT LDS layout (R5-exact, 67072 B)
#define OFF_P   0        /* P bf16 hi (pass A) / lo (pass B) [112][256B] */
#define OFF_HTH 28672    /* hT hi [32][256B] */
#define OFF_HTL 36864
#define OFF_WTH 45056    /* WT hi [32][256B] */
#define OFF_WTL 53248
#define OFF_AB  61440    /* adjacency bitmask [100][4 u32] (pad 112) */
#define OFF_ASV 63232    /* a-vector 64 f32 */
#define OFF_ESV 63488    /* e_src [128] f32 */
#define OFF_EDV 64000    /* e_dst [128] f32 */
#define OFF_PRT 64512    /* rowsum partials [4][128] f32 */
#define OFF_INV 66560    /* 1/rowsum [128] f32 */
#define GAT_LDS 67072

// ---------------------------------------------------------------------------
// pack_A: adjacency -> 128-bit masks, once per b (not per head).
// ---------------------------------------------------------------------------
__global__ __launch_bounds__(256) void pack_A(const float* __restrict__ A, uint* __restrict__ AW)
{
    const int b = blockIdx.x;
    const float4* Ab = (const float4*)(A + (size_t)b * 10000);
    for (int t = threadIdx.x; t < 400; t += 256) {
        const int row = t >> 2, word = t & 3;
        uint bits = 0;
        if (word < 3) {
            #pragma unroll
            for (int j = 0; j < 8; ++j) {
                float4 v = Ab[row * 25 + word * 8 + j];
                uint b4 = (v.x > 0.f ? 1u : 0u) | (v.y > 0.f ? 2u : 0u)
                        | (v.z > 0.f ? 4u : 0u) | (v.w > 0.f ? 8u : 0u);
                bits |= b4 << (j * 4);
            }
        } else {
            float4 v = Ab[row * 25 + 24];   // cols 96..99; 100..127 stay 0
            bits = (v.x > 0.f ? 1u : 0u) | (v.y > 0.f ? 2u : 0u)
                 | (v.z > 0.f ? 4u : 0u) | (v.w > 0.f ? 8u : 0u);
        }
        AW[(size_t)b * 400 + t] = bits;
    }
}

// ---------------------------------------------------------------------------
// Fused GAT layer v2.1 (R5-exact, proven): per (b, head) block, 512 thr.
// ---------------------------------------------------------------------------
template<int F, int KD>
__global__ __launch_bounds__(512, 4) void gat_fused(
    const float* __restrict__ xin,   // [B][100][F]
    const uint*  __restrict__ AW,    // [B][100][4] packed adjacency
    const float* __restrict__ W,     // [H][F][32]
    const float* __restrict__ av,    // [H][64]
    float* __restrict__ xout)        // [B][100][128]
{
    extern __shared__ char smem[];
    char*  Pb  = smem + OFF_P;
    char*  HTH = smem + OFF_HTH;
    char*  HTL = smem + OFF_HTL;
    char*  WTH = smem + OFF_WTH;
    char*  WTL = smem + OFF_WTL;
    uint*  ABu = (uint*)(smem + OFF_AB);
    float* ASV = (float*)(smem + OFF_ASV);
    float* ESV = (float*)(smem + OFF_ESV);
    float* EDV = (float*)(smem + OFF_EDV);
    float* PRT = (float*)(smem + OFF_PRT);
    float* INV = (float*)(smem + OFF_INV);

    const int tid = threadIdx.x;
    // XCD-grouped swizzle: 4 head-blocks of one b land on one XCD, adjacent slots
    const int task = (blockIdx.x & 7) * 512 + (blockIdx.x >> 3);
    const int b = task >> 2, hd = task & 3;
    const int w = tid >> 6, lane = tid & 63;
    const int c16 = lane & 15, r16 = lane >> 4;

    const float* xg = xin + (size_t)b * Nn * F;

    if (F == 65) {   // zero WT for k-padding (f 65..95)
        uint4 z = make_uint4(0, 0, 0, 0);
        #pragma unroll
        for (int i = 0; i < 2; ++i)
            *(uint4*)(smem + OFF_WTH + (i * 512 + tid) * 16) = z;
        __syncthreads();
    }

    // ---- prefetch x fragments (F=128 path) before the staging barrier
    const int nA = (w * 16 + c16 < 100) ? (w * 16 + c16) : 99;
    float4 xpre[8];
    if (F == 128 && w < 7) {
        #pragma unroll
        for (int d = 0; d < 4; ++d) {
            const float* px = xg + (size_t)nA * 128 + d * 32 + r16 * 8;
            xpre[2 * d]     = *(const float4*)(px);
            xpre[2 * d + 1] = *(const float4*)(px + 4);
        }
    }

    // ---- ph1: stage WT (RNE hi/lo, transposed), ASV, AB copy, tail zeroing
    {
        const float4* Wg4 = (const float4*)(W + (size_t)hd * F * 32);
        #pragma unroll
        for (int it = 0; it < 2; ++it) {
            int id = it * 512 + tid;            // F*8 chunks (f, o4)
            if (id < F * 8) {
                int f = id >> 3, o4 = (id & 7) * 4;
                float4 v = Wg4[id];
                ushort h0 = f2bf(v.x), l0 = f2bf(v.x - bf2f(h0));
                ushort h1 = f2bf(v.y), l1 = f2bf(v.y - bf2f(h1));
                ushort h2 = f2bf(v.z), l2 = f2bf(v.z - bf2f(h2));
                ushort h3 = f2bf(v.w), l3 = f2bf(v.w - bf2f(h3));
                *(ushort*)(WTH + swzb(o4 + 0, 2 * f)) = h0; *(ushort*)(WTL + swzb(o4 + 0, 2 * f)) = l0;
                *(ushort*)(WTH + swzb(o4 + 1, 2 * f)) = h1; *(ushort*)(WTL + swzb(o4 + 1, 2 * f)) = l1;
                *(ushort*)(WTH + swzb(o4 + 2, 2 * f)) = h2; *(ushort*)(WTL + swzb(o4 + 2, 2 * f)) = l2;
                *(ushort*)(WTH + swzb(o4 + 3, 2 * f)) = h3; *(ushort*)(WTL + swzb(o4 + 3, 2 * f)) = l3;
            }
        }
    }
    if (tid < 64) ASV[tid] = av[hd * 64 + tid];
    {
        int idA = tid - 64;
        if (idA >= 0 && idA < 400) ABu[idA] = AW[(size_t)b * 400 + idA];
    }
    if (tid < 400) {    // zero P logical bytes 192..255 (m 96..127) rows 0..99
        const int row = tid >> 2, slot = 12 + (tid & 3);
        *(uint4*)(Pb + row * 256 + ((slot * 16) ^ ((row & 15) << 4))) = make_uint4(0, 0, 0, 0);
    }
    if (tid < 256) {    // zero hT logical bytes 192..255 (cols 96..127; 96..99 rewritten in ph2)
        char* base = (tid & 128) ? HTL : HTH;
        const int rr = (tid >> 2) & 31, sl = 12 + (tid & 3);
        *(uint4*)(base + swzb(rr, sl * 16)) = make_uint4(0, 0, 0, 0);
    }
    if (tid >= 464 && tid < 492) { ESV[tid - 364] = 0.f; EDV[tid - 364] = 0.f; }  // idx 100..127
    __syncthreads();

    // ---- ph2: MFMA-1 h = x*W (wave w owns rows w*16..+15, both o-halves)
    if (w < 7) {
        f32x4 acc0 = {0.f, 0.f, 0.f, 0.f}, acc1 = {0.f, 0.f, 0.f, 0.f};
        #pragma unroll
        for (int d = 0; d < KD; ++d) {
            float xv[8];
            if (F == 128) {
                float4 v0 = xpre[2 * d], v1 = xpre[2 * d + 1];
                xv[0] = v0.x; xv[1] = v0.y; xv[2] = v0.z; xv[3] = v0.w;
                xv[4] = v1.x; xv[5] = v1.y; xv[6] = v1.z; xv[7] = v1.w;
            } else {
                const int f0 = d * 32 + r16 * 8;
                #pragma unroll
                for (int j = 0; j < 8; ++j) {
                    int f = f0 + j;
                    xv[j] = (f < 65) ? xg[(size_t)nA * 65 + f] : 0.f;
                }
            }
            uint hu[4], lu[4];
            #pragma unroll
            for (int i = 0; i < 4; ++i) {
                uint u0 = __float_as_uint(xv[2 * i]);
                uint u1 = __float_as_uint(xv[2 * i + 1]);
                float l0 = xv[2 * i]     - __uint_as_float(u0 & 0xFFFF0000u);
                float l1 = xv[2 * i + 1] - __uint_as_float(u1 & 0xFFFF0000u);
                hu[i] = __builtin_amdgcn_perm(u1, u0, 0x07060302u);
                lu[i] = __builtin_amdgcn_perm(__float_as_uint(l1), __float_as_uint(l0), 0x07060302u);
            }
            short8 ah = mk8(hu[0], hu[1], hu[2], hu[3]);
            short8 al = mk8(lu[0], lu[1], lu[2], lu[3]);
            const int kb = d * 64 + r16 * 16;
            short8 bh0 = *(const short8*)(WTH + swzb(c16, kb));
            short8 bl0 = *(const short8*)(WTL + swzb(c16, kb));
            short8 bh1 = *(const short8*)(WTH + swzb(16 + c16, kb));
            short8 bl1 = *(const short8*)(WTL + swzb(16 + c16, kb));
            acc0 = __builtin_amdgcn_mfma_f32_16x16x32_bf16(ah, bh0, acc0, 0, 0, 0);
            acc0 = __builtin_amdgcn_mfma_f32_16x16x32_bf16(al, bh0, acc0, 0, 0, 0);
            acc0 = __builtin_amdgcn_mfma_f32_16x16x32_bf16(ah, bl0, acc0, 0, 0, 0);
            acc1 = __builtin_amdgcn_mfma_f32_16x16x32_bf16(ah, bh1, acc1, 0, 0, 0);
            acc1 = __builtin_amdgcn_mfma_f32_16x16x32_bf16(al, bh1, acc1, 0, 0, 0);
            acc1 = __builtin_amdgcn_mfma_f32_16x16x32_bf16(ah, bl1, acc1, 0, 0, 0);
        }
        const int n0 = w * 16 + r16 * 4;
        if (n0 < 100) {   // hT split write: rows o, cols n0..n0+3 (all <100)
            ushort h0 = f2bf(acc0[0]), l0 = f2bf(acc0[0] - bf2f(h0));
            ushort h1 = f2bf(acc0[1]), l1 = f2bf(acc0[1] - bf2f(h1));
            ushort h2 = f2bf(acc0[2]), l2 = f2bf(acc0[2] - bf2f(h2));
            ushort h3 = f2bf(acc0[3]), l3 = f2bf(acc0[3] - bf2f(h3));
            uint2 uh; uh.x = (uint)h0 | ((uint)h1 << 16); uh.y = (uint)h2 | ((uint)h3 << 16);
            uint2 ul; ul.x = (uint)l0 | ((uint)l1 << 16); ul.y = (uint)l2 | ((uint)l3 << 16);
            *(uint2*)(HTH + swzb(c16, 2 * n0)) = uh;
            *(uint2*)(HTL + swzb(c16, 2 * n0)) = ul;
            h0 = f2bf(acc1[0]); l0 = f2bf(acc1[0] - bf2f(h0));
            h1 = f2bf(acc1[1]); l1 = f2bf(acc1[1] - bf2f(h1));
            h2 = f2bf(acc1[2]); l2 = f2bf(acc1[2] - bf2f(h2));
            h3 = f2bf(acc1[3]); l3 = f2bf(acc1[3] - bf2f(h3));
            uh.x = (uint)h0 | ((uint)h1 << 16); uh.y = (uint)h2 | ((uint)h3 << 16);
            ul.x = (uint)l0 | ((uint)l1 << 16); ul.y = (uint)l2 | ((uint)l3 << 16);
            *(uint2*)(HTH + swzb(16 + c16, 2 * n0)) = uh;
            *(uint2*)(HTL + swzb(16 + c16, 2 * n0)) = ul;
        }
        // es/ed: reduce acc*a over 32 o's (both halves pre-summed, 16-lane xor)
        const float as0 = ASV[c16], as1 = ASV[16 + c16];
        const float ad0 = ASV[32 + c16], ad1 = ASV[48 + c16];
        #pragma unroll
        for (int r = 0; r < 4; ++r) {
            float vs = acc0[r] * as0 + acc1[r] * as1;
            float vd = acc0[r] * ad0 + acc1[r] * ad1;
            #pragma unroll
            for (int mk = 1; mk <= 8; mk <<= 1) {
                vs += __shfl_xor(vs, mk, 64);
                vd += __shfl_xor(vd, mk, 64);
            }
            if (c16 == 0 && n0 + r < 100) { ESV[n0 + r] = vs; EDV[n0 + r] = vd; }
        }
    }
    __syncthreads();

    // ---- ph4: e-pass (uniform 7 chunks; m>=100 -> p=0). Keep p in registers.
    const int q4 = w & 3, nset4 = w >> 2;
    const int n4 = nset4 * 64 + lane;
    const bool val4 = n4 < 100;
    const int m0q = q4 * 28;
    float pv[28];
    {
        float esn = 0.f;
        uint a0 = 0, a1 = 0, a2 = 0, a3 = 0;
        if (val4) {
            esn = ESV[n4];
            uint4 ab = *(const uint4*)(ABu + n4 * 4);
            a0 = ab.x; a1 = ab.y; a2 = ab.z; a3 = ab.w;
        }
        float rsum = 0.f;
        #pragma unroll
        for (int mc = 0; mc < 7; ++mc) {
            uint wh0 = 0, wh1 = 0;
            #pragma unroll
            for (int j = 0; j < 4; ++j) {
                int m = m0q + mc * 4 + j;        // < 112; EDV[>=100] zeroed
                float e = esn + EDV[m];
                e = e > 0.f ? e : 0.2f * e;      // LeakyReLU
                int wsel = m >> 5;
                uint wrd = wsel == 0 ? a0 : (wsel == 1 ? a1 : (wsel == 2 ? a2 : a3));
                float p = ((wrd >> (m & 31)) & 1u) ? __expf(e) : 0.f;
                pv[mc * 4 + j] = p;
                rsum += p;
                ushort pb = f2bf(p);
                if (j == 0)      wh0 |= pb;
                else if (j == 1) wh0 |= (uint)pb << 16;
                else if (j == 2) wh1 |= pb;
                else             wh1 |= (uint)pb << 16;
            }
            if (val4) {
                uint2 uw; uw.x = wh0; uw.y = wh1;
                const int byte = 2 * m0q + 8 * mc;
                *(uint2*)(Pb + n4 * 256 + (byte ^ ((n4 & 15) << 4))) = uw;
            }
        }
        if (val4) PRT[q4 * 128 + n4] = rsum;
    }
    __syncthreads();

    // ---- ph5: inverse row sums
    if (tid < 100)
        INV[tid] = 1.f / (PRT[tid] + PRT[128 + tid] + PRT[256 + tid] + PRT[384 + tid]);
    __syncthreads();

    // ---- ph6a: acc += P_hi * (h_hi + h_lo)
    f32x4 acc0 = {0.f, 0.f, 0.f, 0.f}, acc1 = {0.f, 0.f, 0.f, 0.f};
    if (w < 7) {
        #pragma unroll
        for (int d = 0; d < 4; ++d) {
            const int kb = d * 64 + r16 * 16;
            short8 pa  = *(const short8*)(Pb + nA * 256 + (kb ^ ((nA & 15) << 4)));
            short8 bh0 = *(const short8*)(HTH + swzb(c16, kb));
            short8 bl0 = *(const short8*)(HTL + swzb(c16, kb));
            short8 bh1 = *(const short8*)(HTH + swzb(16 + c16, kb));
            short8 bl1 = *(const short8*)(HTL + swzb(16 + c16, kb));
            acc0 = __builtin_amdgcn_mfma_f32_16x16x32_bf16(pa, bh0, acc0, 0, 0, 0);
            acc0 = __builtin_amdgcn_mfma_f32_16x16x32_bf16(pa, bl0, acc0, 0, 0, 0);
            acc1 = __builtin_amdgcn_mfma_f32_16x16x32_bf16(pa, bh1, acc1, 0, 0, 0);
            acc1 = __builtin_amdgcn_mfma_f32_16x16x32_bf16(pa, bl1, acc1, 0, 0, 0);
        }
    }
    __syncthreads();

    // ---- ph4b: rewrite P region with lo residuals (from registers)
    {
        #pragma unroll
        for (int mc = 0; mc < 7; ++mc) {
            uint wl0 = 0, wl1 = 0;
            #pragma unroll
            for (int j = 0; j < 4; ++j) {
                float p = pv[mc * 4 + j];
                float lo = p - bf2f(f2bf(p));
                ushort lb = f2bf(lo);
                if (j == 0)      wl0 |= lb;
                else if (j == 1) wl0 |= (uint)lb << 16;
                else if (j == 2) wl1 |= lb;
                else             wl1 |= (uint)lb << 16;
            }
            if (val4) {
                uint2 uw; uw.x = wl0; uw.y = wl1;
                const int byte = 2 * m0q + 8 * mc;
                *(uint2*)(Pb + n4 * 256 + (byte ^ ((n4 & 15) << 4))) = uw;
            }
        }
    }
    __syncthreads();

    // ---- ph6b: acc += P_lo * h_hi; epilogue elu((acc)*inv) -> global
    if (w < 7) {
        #pragma unroll
        for (int d = 0; d < 4; ++d) {
            const int kb = d * 64 + r16 * 16;
            short8 pl  = *(const short8*)(Pb + nA * 256 + (kb ^ ((nA & 15) << 4)));
            short8 bh0 = *(const short8*)(HTH + swzb(c16, kb));
            short8 bh1 = *(const short8*)(HTH + swzb(16 + c16, kb));
            acc0 = __builtin_amdgcn_mfma_f32_16x16x32_bf16(pl, bh0, acc0, 0, 0, 0);
            acc1 = __builtin_amdgcn_mfma_f32_16x16x32_bf16(pl, bh1, acc1, 0, 0, 0);
        }
        const int n0 = w * 16 + r16 * 4;
        float* xo = xout + (size_t)b * Nn * Dd + hd * 32;
        #pragma unroll
        for (int r = 0; r < 4; ++r) {
            int n = n0 + r;
            if (n < 100) {
                const float inv = INV[n];
                float v0 = acc0[r] * inv; v0 = v0 > 0.f ? v0 : expm1f(v0);
                float v1 = acc1[r] * inv; v1 = v1 > 0.f ? v1 : expm1f(v1);
                xo[(size_t)n * Dd + c16] = v0;
                xo[(size_t)n * Dd + 16 + c16] = v1;
            }
        }
    }
}

// ---------------------------------------------------------------------------
// GEMM1 split-bf16 MFMA, 128x128 tile, BK=64, SK=8 -> 512 blocks, 2/CU.
// FIX: B-staging second 16B half must use bofs(bn, kq4*32+16) (swizzle-aware),
// not bb+16 — bb+16 lands in the wrong physical slot for odd (bn>>3).
// ---------------------------------------------------------------------------
#define G1_LDS 73728
__device__ __forceinline__ int aofs(int r, int kb) { return r * 144 + kb; }
__device__ __forceinline__ int bofs(int n, int kb) { return n * 144 + (kb ^ (((n >> 3) & 1) << 4)); }

__global__ __launch_bounds__(512, 4) void gemm1_mfma(
    const float* __restrict__ Ag, const float* __restrict__ Bg,
    float* __restrict__ part)
{
    extern __shared__ char sm[];
    char* AH = sm;             // [128][144]
    char* AL = sm + 18432;
    char* BH = sm + 36864;     // [128][144]
    char* BL = sm + 55296;

    const int tid = threadIdx.x;
    const int pb = blockIdx.x;
    const int task = (pb & 7) * 64 + (pb >> 3);
    const int mb = task & 7, g = task >> 3;
    const int nb = g & 7, z = g >> 3;
    const int m0 = mb * 128, n0 = nb * 128;
    const int k0 = z * 1600;

    const int w = tid >> 6, lane = tid & 63;
    const int wn = w & 3, wm = w >> 2;               // wave tile 64m x 32n
    const int c16 = lane & 15, r16 = lane >> 4;

    const int ra = tid >> 2, kq = tid & 3;           // A: row, 16-k quarter
    const int bn = tid >> 2, kq4 = tid & 3;          // B: col n, 16-k quarter

    const float* Aptr = Ag + (size_t)(m0 + ra) * K1 + k0 + kq * 16;
    const float* Bptr = Bg + (size_t)(k0 + kq4 * 16) * N1 + n0 + bn;

    f32x4 acc[4][2];
    #pragma unroll
    for (int i = 0; i < 4; ++i)
        #pragma unroll
        for (int j = 0; j < 2; ++j) acc[i][j] = (f32x4){0.f, 0.f, 0.f, 0.f};

    float a_reg[16];
    float b_reg[16];
    #pragma unroll
    for (int q = 0; q < 4; ++q) *(float4*)&a_reg[q * 4] = *(const float4*)(Aptr + q * 4);
    #pragma unroll
    for (int j = 0; j < 16; ++j) b_reg[j] = Bptr[(size_t)j * N1];

    for (int it = 0; it < 25; ++it) {
        __syncthreads();   // previous iter's MFMA reads done -> LDS writable
        {
            uint hi[8], lo[8];
            #pragma unroll
            for (int i = 0; i < 8; ++i) {
                uint u0 = __float_as_uint(a_reg[2 * i]);
                uint u1 = __float_as_uint(a_reg[2 * i + 1]);
                float l0 = a_reg[2 * i]     - __uint_as_float(u0 & 0xFFFF0000u);
                float l1 = a_reg[2 * i + 1] - __uint_as_float(u1 & 0xFFFF0000u);
                hi[i] = __builtin_amdgcn_perm(u1, u0, 0x07060302u);
                lo[i] = __builtin_amdgcn_perm(__float_as_uint(l1), __float_as_uint(l0), 0x07060302u);
            }
            const int ab = aofs(ra, kq * 32);   // aofs has no XOR: +16 is safe
            *(uint4*)(AH + ab)      = make_uint4(hi[0], hi[1], hi[2], hi[3]);
            *(uint4*)(AH + ab + 16) = make_uint4(hi[4], hi[5], hi[6], hi[7]);
            *(uint4*)(AL + ab)      = make_uint4(lo[0], lo[1], lo[2], lo[3]);
            *(uint4*)(AL + ab + 16) = make_uint4(lo[4], lo[5], lo[6], lo[7]);
        }
        {
            uint hi[8], lo[8];
            #pragma unroll
            for (int i = 0; i < 8; ++i) {
                uint u0 = __float_as_uint(b_reg[2 * i]);
                uint u1 = __float_as_uint(b_reg[2 * i + 1]);
                float l0 = b_reg[2 * i]     - __uint_as_float(u0 & 0xFFFF0000u);
                float l1 = b_reg[2 * i + 1] - __uint_as_float(u1 & 0xFFFF0000u);
                hi[i] = __builtin_amdgcn_perm(u1, u0, 0x07060302u);
                lo[i] = __builtin_amdgcn_perm(__float_as_uint(l1), __float_as_uint(l0), 0x07060302u);
            }
            const int bb0 = bofs(bn, kq4 * 32);        // swizzle-aware per-16B
            const int bb1 = bofs(bn, kq4 * 32 + 16);   // FIX (was bb0 + 16)
            *(uint4*)(BH + bb0) = make_uint4(hi[0], hi[1], hi[2], hi[3]);
            *(uint4*)(BH + bb1) = make_uint4(hi[4], hi[5], hi[6], hi[7]);
            *(uint4*)(BL + bb0) = make_uint4(lo[0], lo[1], lo[2], lo[3]);
            *(uint4*)(BL + bb1) = make_uint4(lo[4], lo[5], lo[6], lo[7]);
        }
        __syncthreads();   // LDS tile ready

        if (it < 24) {
            Aptr += 64;
            Bptr += (size_t)64 * N1;
            #pragma unroll
            for (int q = 0; q < 4; ++q) *(float4*)&a_reg[q * 4] = *(const float4*)(Aptr + q * 4);
            #pragma unroll
            for (int j = 0; j < 16; ++j) b_reg[j] = Bptr[(size_t)j * N1];
        }

        #pragma unroll
        for (int ks = 0; ks < 2; ++ks) {
            const int kb = ks * 64 + r16 * 16;
            short8 bh[2], bl[2];
            #pragma unroll
            for (int nf = 0; nf < 2; ++nf) {
                const int nr = wn * 32 + nf * 16 + c16;
                bh[nf] = *(const short8*)(BH + bofs(nr, kb));
                bl[nf] = *(const short8*)(BL + bofs(nr, kb));
            }
            #pragma unroll
            for (int mf = 0; mf < 4; ++mf) {
                const int ar = wm * 64 + mf * 16 + c16;
                short8 ah = *(const short8*)(AH + aofs(ar, kb));
                short8 al = *(const short8*)(AL + aofs(ar, kb));
                #pragma unroll
                for (int nf = 0; nf < 2; ++nf) {
                    acc[mf][nf] = __builtin_amdgcn_mfma_f32_16x16x32_bf16(ah, bh[nf], acc[mf][nf], 0, 0, 0);
                    acc[mf][nf] = __builtin_amdgcn_mfma_f32_16x16x32_bf16(al, bh[nf], acc[mf][nf], 0, 0, 0);
                    acc[mf][nf] = __builtin_amdgcn_mfma_f32_16x16x32_bf16(ah, bl[nf], acc[mf][nf], 0, 0, 0);
                }
            }
        }
    }

    float* pz = part + (size_t)z * M1 * N1;
    #pragma unroll
    for (int mf = 0; mf < 4; ++mf) {
        const int m = m0 + wm * 64 + mf * 16 + r16 * 4;
        #pragma unroll
        for (int nf = 0; nf < 2; ++nf) {
            const int n = n0 + wn * 32 + nf * 16 + c16;
            #pragma unroll
            for (int r = 0; r < 4; ++r)
                pz[(size_t)(m + r) * N1 + n] = acc[mf][nf][r];
        }
    }
}

// Reduce split-K partials + bias + BN(eval) + ReLU
__global__ __launch_bounds__(256) void bn1_reduce(
    const float* __restrict__ part, const float* __restrict__ pb1,
    const float* __restrict__ g1, const float* __restrict__ be1,
    float* __restrict__ y1)
{
    const int idx = blockIdx.x * 256 + threadIdx.x;
    float s = 0.f;
    #pragma unroll
    for (int z = 0; z < SK; ++z) s += part[(size_t)z * M1 * N1 + idx];
    const int j = idx & (N1 - 1);
    s += pb1[j];
    const float rbn = 1.0f / sqrtf(1.0f + 1e-5f);
    s = g1[j] * s * rbn + be1[j];
    y1[idx] = fmaxf(s, 0.f);
}

// GEMM2 (1024x1024)x(1024x128) + bias + BN + ReLU -> d_out
__global__ __launch_bounds__(128) void gemm2_bn(
    const float* __restrict__ y1, const float* __restrict__ W2,
    const float* __restrict__ pb2, const float* __restrict__ g2,
    const float* __restrict__ be2, float* __restrict__ out)
{
    __shared__ __align__(16) float xr[1024];
    const int tid = threadIdx.x, m = blockIdx.x;
    for (int i = tid; i < 1024; i += 128) xr[i] = y1[(size_t)m * 1024 + i];
    __syncthreads();
    float acc = 0.f;
    #pragma unroll 8
    for (int k = 0; k < 1024; ++k) acc += xr[k] * W2[k * 128 + tid];
    acc += pb2[tid];
    const float rbn = 1.0f / sqrtf(1.0f + 1e-5f);
    acc = g2[tid] * acc * rbn + be2[tid];
    out[(size_t)m * 128 + tid] = fmaxf(acc, 0.f);
}

// ---------------------------------------------------------------------------
extern "C" void kernel_launch(void* const* d_in, const int* in_sizes, int n_in,
                              void* d_out, int out_size, void* d_ws, size_t ws_size,
                              hipStream_t stream)
{
    const float* X   = (const float*)d_in[0];
    const float* A   = (const float*)d_in[1];
    const float* W0  = (const float*)d_in[2];
    const float* a0  = (const float*)d_in[3];
    const float* Wl  = (const float*)d_in[4];
    const float* al  = (const float*)d_in[5];
    const float* pW1 = (const float*)d_in[6];
    const float* pb1 = (const float*)d_in[7];
    const float* g1  = (const float*)d_in[8];
    const float* be1 = (const float*)d_in[9];
    const float* pW2 = (const float*)d_in[10];
    const float* pb2 = (const float*)d_in[11];
    const float* g2  = (const float*)d_in[12];
    const float* be2 = (const float*)d_in[13];
    float* out = (float*)d_out;

    // ws: xa(52.4MB) | xb(52.4MB, reused as gemm1 partials) | y1(4.2MB, AW overlay)
    float* ws = (float*)d_ws;
    float* xa = ws;
    float* xb = xa + (size_t)Bb * Nn * Dd;
    float* y1 = xb + (size_t)Bb * Nn * Dd;
    float* part = xb;
    uint*  AW = (uint*)y1;          // packed adjacency, dead before bn1 writes y1

    (void)hipFuncSetAttribute(reinterpret_cast<const void*>(gat_fused<65, 3>),
                              hipFuncAttributeMaxDynamicSharedMemorySize, GAT_LDS);
    (void)hipFuncSetAttribute(reinterpret_cast<const void*>(gat_fused<128, 4>),
                              hipFuncAttributeMaxDynamicSharedMemorySize, GAT_LDS);
    (void)hipFuncSetAttribute(reinterpret_cast<const void*>(gemm1_mfma),
                              hipFuncAttributeMaxDynamicSharedMemorySize, G1_LDS);

    pack_A<<<dim3(Bb), 256, 0, stream>>>(A, AW);
    gat_fused<65, 3><<<dim3(Bb * Hh), 512, GAT_LDS, stream>>>(X, AW, W0, a0, xa);
    const float* src = xa; float* dst = xb;
    for (int l = 1; l < 5; ++l) {
        gat_fused<128, 4><<<dim3(Bb * Hh), 512, GAT_LDS, stream>>>(
            src, AW, Wl + (size_t)(l - 1) * Hh * Dd * Oo, al + (size_t)(l - 1) * Hh * 2 * Oo, dst);
        float* t = (float*)src; src = dst; dst = t;
    }
    gemm1_mfma<<<dim3(512), 512, G1_LDS, stream>>>(src, pW1, part);
    bn1_reduce<<<dim3((M1 * N1) / 256), 256, 0, stream>>>(part, pb1, g1, be1, y1);
    gemm2_bn<<<dim3(M1), 128, 0, stream>>>(y1, pW2, pb2, g2, be2, out);
}

// Round 10
// 477.318 us; speedup vs baseline: 3.7388x; 1.2269x over previous
//
#include <hip/hip_runtime.h>
#include <math.h>

typedef __attribute__((ext_vector_type(8))) short short8;   // 8 bf16 (4 VGPR) MFMA A/B frag
typedef __attribute__((ext_vector_type(4))) float f32x4;    // MFMA C/D frag
typedef __attribute__((ext_vector_type(4))) uint  uint4v;

constexpr int Bb = 1024, Nn = 100, Hh = 4, Oo = 32, Dd = 128;
constexpr int K1 = 12800, N1 = 1024, M1 = 1024, SK = 8;

// bf16 round-to-nearest-even helpers
__device__ __forceinline__ ushort f2bf(float f) {
    uint u = __float_as_uint(f);
    return (ushort)((u + 0x7FFFu + ((u >> 16) & 1u)) >> 16);
}
__device__ __forceinline__ float bf2f(ushort h) {
    return __uint_as_float(((uint)h) << 16);
}
__device__ __forceinline__ short8 mk8(uint a, uint b, uint c, uint d) {
    uint4v v = {a, b, c, d};
    return __builtin_bit_cast(short8, v);
}
// swizzle within [rows][256B] LDS tiles: XOR 16B-slot bits with row&7
__device__ __forceinline__ int swzb(int row, int kb)  { return row * 256 + (kb ^ ((row & 7) << 4)); }

// GAT LDS layout (dynamic, 36352 B -> 4 blocks/CU if VGPRs allow)
#define OFF_HTH 0        /* hT hi [32][256B] */
#define OFF_HTL 8192
#define OFF_WTH 16384    /* WT hi [32][256B] */
#define OFF_WTL 24576
#define OFF_AB  32768    /* adjacency bitmask [112][4 u32] (448 words, >=400 zeroed) */
#define OFF_ASV 34560    /* a-vector 64 f32 */
#define OFF_ESV 34816    /* e_src [128] f32 */
#define OFF_EDV 35328    /* e_dst [128] f32 */
#define OFF_INV 35840    /* 1/rowsum [128] f32 */
#define GAT_LDS 36352

// ---------------------------------------------------------------------------
// pack_A: adjacency -> 128-bit masks, once per b (not per head).
// ---------------------------------------------------------------------------
__global__ __launch_bounds__(256) void pack_A(const float* __restrict__ A, uint* __restrict__ AW)
{
    const int b = blockIdx.x;
    const float4* Ab = (const float4*)(A + (size_t)b * 10000);
    for (int t = threadIdx.x; t < 400; t += 256) {
        const int row = t >> 2, word = t & 3;
        uint bits = 0;
        if (word < 3) {
            #pragma unroll
            for (int j = 0; j < 8; ++j) {
                float4 v = Ab[row * 25 + word * 8 + j];
                uint b4 = (v.x > 0.f ? 1u : 0u) | (v.y > 0.f ? 2u : 0u)
                        | (v.z > 0.f ? 4u : 0u) | (v.w > 0.f ? 8u : 0u);
                bits |= b4 << (j * 4);
            }
        } else {
            float4 v = Ab[row * 25 + 24];   // cols 96..99; 100..127 stay 0
            bits = (v.x > 0.f ? 1u : 0u) | (v.y > 0.f ? 2u : 0u)
                 | (v.z > 0.f ? 4u : 0u) | (v.w > 0.f ? 8u : 0u);
        }
        AW[(size_t)b * 400 + t] = bits;
    }
}

// ---------------------------------------------------------------------------
// Fused GAT layer v3.1: per (b, head) block, 512 thr, 3 barriers.
//   In-register P feeding MFMA-2 directly; rowsum -> INV via LDS (+barrier);
//   epilogue reads INV[n]. 1/0 never consumed (INV written only for np<100).
// ---------------------------------------------------------------------------
template<int F, int KD>
__global__ __launch_bounds__(512, 4) void gat_fused(
    const float* __restrict__ xin,   // [B][100][F]
    const uint*  __restrict__ AW,    // [B][100][4] packed adjacency
    const float* __restrict__ W,     // [H][F][32]
    const float* __restrict__ av,    // [H][64]
    float* __restrict__ xout)        // [B][100][128]
{
    extern __shared__ char smem[];
    char*  HTH = smem + OFF_HTH;
    char*  HTL = smem + OFF_HTL;
    char*  WTH = smem + OFF_WTH;
    char*  WTL = smem + OFF_WTL;
    uint*  ABu = (uint*)(smem + OFF_AB);
    float* ASV = (float*)(smem + OFF_ASV);
    float* ESV = (float*)(smem + OFF_ESV);
    float* EDV = (float*)(smem + OFF_EDV);
    float* INV = (float*)(smem + OFF_INV);

    const int tid = threadIdx.x;
    // XCD-grouped swizzle: 4 head-blocks of one b land on one XCD, adjacent slots
    const int task = (blockIdx.x & 7) * 512 + (blockIdx.x >> 3);
    const int b = task >> 2, hd = task & 3;
    const int w = tid >> 6, lane = tid & 63;
    const int c16 = lane & 15, r16 = lane >> 4;

    const float* xg = xin + (size_t)b * Nn * F;

    if (F == 65) {   // zero WT for k-padding (f 65..95)
        uint4 z = make_uint4(0, 0, 0, 0);
        #pragma unroll
        for (int i = 0; i < 2; ++i)
            *(uint4*)(smem + OFF_WTH + (i * 512 + tid) * 16) = z;
        __syncthreads();
    }

    // ---- prefetch x fragments (F=128 path) before the staging barrier
    const int nA = (w * 16 + c16 < 100) ? (w * 16 + c16) : 99;
    float4 xpre[8];
    if (F == 128 && w < 7) {
        #pragma unroll
        for (int d = 0; d < 4; ++d) {
            const float* px = xg + (size_t)nA * 128 + d * 32 + r16 * 8;
            xpre[2 * d]     = *(const float4*)(px);
            xpre[2 * d + 1] = *(const float4*)(px + 4);
        }
    }

    // ---- ph1: stage WT (RNE hi/lo, transposed), ASV, AB copy, tail zeroing
    {
        const float4* Wg4 = (const float4*)(W + (size_t)hd * F * 32);
        #pragma unroll
        for (int it = 0; it < 2; ++it) {
            int id = it * 512 + tid;            // F*8 chunks (f, o4)
            if (id < F * 8) {
                int f = id >> 3, o4 = (id & 7) * 4;
                float4 v = Wg4[id];
                ushort h0 = f2bf(v.x), l0 = f2bf(v.x - bf2f(h0));
                ushort h1 = f2bf(v.y), l1 = f2bf(v.y - bf2f(h1));
                ushort h2 = f2bf(v.z), l2 = f2bf(v.z - bf2f(h2));
                ushort h3 = f2bf(v.w), l3 = f2bf(v.w - bf2f(h3));
                *(ushort*)(WTH + swzb(o4 + 0, 2 * f)) = h0; *(ushort*)(WTL + swzb(o4 + 0, 2 * f)) = l0;
                *(ushort*)(WTH + swzb(o4 + 1, 2 * f)) = h1; *(ushort*)(WTL + swzb(o4 + 1, 2 * f)) = l1;
                *(ushort*)(WTH + swzb(o4 + 2, 2 * f)) = h2; *(ushort*)(WTL + swzb(o4 + 2, 2 * f)) = l2;
                *(ushort*)(WTH + swzb(o4 + 3, 2 * f)) = h3; *(ushort*)(WTL + swzb(o4 + 3, 2 * f)) = l3;
            }
        }
    }
    if (tid < 64) ASV[tid] = av[hd * 64 + tid];
    {
        const int idA = tid - 64;
        if (idA >= 0 && idA < 400) ABu[idA] = AW[(size_t)b * 400 + idA];
        else if (idA >= 400 && idA < 448) ABu[idA] = 0u;   // rows 100..111 -> mask 0
    }
    if (tid < 256) {    // zero hT cols 96..127 (96..99 rewritten in ph2)
        char* base = (tid & 128) ? HTL : HTH;
        const int rr = (tid >> 2) & 31, sl = 12 + (tid & 3);
        *(uint4*)(base + swzb(rr, sl * 16)) = make_uint4(0, 0, 0, 0);
    }
    if (tid < 28) { ESV[100 + tid] = 0.f; EDV[100 + tid] = 0.f; }
    __syncthreads();

    // ---- ph2: MFMA-1 h = x*W (wave w owns rows w*16..+15, both o-halves)
    if (w < 7) {
        f32x4 acc0 = {0.f, 0.f, 0.f, 0.f}, acc1 = {0.f, 0.f, 0.f, 0.f};
        #pragma unroll
        for (int d = 0; d < KD; ++d) {
            float xv[8];
            if (F == 128) {
                float4 v0 = xpre[2 * d], v1 = xpre[2 * d + 1];
                xv[0] = v0.x; xv[1] = v0.y; xv[2] = v0.z; xv[3] = v0.w;
                xv[4] = v1.x; xv[5] = v1.y; xv[6] = v1.z; xv[7] = v1.w;
            } else {
                const int f0 = d * 32 + r16 * 8;
                #pragma unroll
                for (int j = 0; j < 8; ++j) {
                    int f = f0 + j;
                    xv[j] = (f < 65) ? xg[(size_t)nA * 65 + f] : 0.f;
                }
            }
            uint hu[4], lu[4];
            #pragma unroll
            for (int i = 0; i < 4; ++i) {
                uint u0 = __float_as_uint(xv[2 * i]);
                uint u1 = __float_as_uint(xv[2 * i + 1]);
                float l0 = xv[2 * i]     - __uint_as_float(u0 & 0xFFFF0000u);
                float l1 = xv[2 * i + 1] - __uint_as_float(u1 & 0xFFFF0000u);
                hu[i] = __builtin_amdgcn_perm(u1, u0, 0x07060302u);
                lu[i] = __builtin_amdgcn_perm(__float_as_uint(l1), __float_as_uint(l0), 0x07060302u);
            }
            short8 ah = mk8(hu[0], hu[1], hu[2], hu[3]);
            short8 al = mk8(lu[0], lu[1], lu[2], lu[3]);
            const int kb = d * 64 + r16 * 16;
            short8 bh0 = *(const short8*)(WTH + swzb(c16, kb));
            short8 bl0 = *(const short8*)(WTL + swzb(c16, kb));
            short8 bh1 = *(const short8*)(WTH + swzb(16 + c16, kb));
            short8 bl1 = *(const short8*)(WTL + swzb(16 + c16, kb));
            acc0 = __builtin_amdgcn_mfma_f32_16x16x32_bf16(ah, bh0, acc0, 0, 0, 0);
            acc0 = __builtin_amdgcn_mfma_f32_16x16x32_bf16(al, bh0, acc0, 0, 0, 0);
            acc0 = __builtin_amdgcn_mfma_f32_16x16x32_bf16(ah, bl0, acc0, 0, 0, 0);
            acc1 = __builtin_amdgcn_mfma_f32_16x16x32_bf16(ah, bh1, acc1, 0, 0, 0);
            acc1 = __builtin_amdgcn_mfma_f32_16x16x32_bf16(al, bh1, acc1, 0, 0, 0);
            acc1 = __builtin_amdgcn_mfma_f32_16x16x32_bf16(ah, bl1, acc1, 0, 0, 0);
        }
        const int n0 = w * 16 + r16 * 4;
        if (n0 < 100) {   // hT split write: rows o, cols n0..n0+3 (all <100)
            ushort h0 = f2bf(acc0[0]), l0 = f2bf(acc0[0] - bf2f(h0));
            ushort h1 = f2bf(acc0[1]), l1 = f2bf(acc0[1] - bf2f(h1));
            ushort h2 = f2bf(acc0[2]), l2 = f2bf(acc0[2] - bf2f(h2));
            ushort h3 = f2bf(acc0[3]), l3 = f2bf(acc0[3] - bf2f(h3));
            uint2 uh; uh.x = (uint)h0 | ((uint)h1 << 16); uh.y = (uint)h2 | ((uint)h3 << 16);
            uint2 ul; ul.x = (uint)l0 | ((uint)l1 << 16); ul.y = (uint)l2 | ((uint)l3 << 16);
            *(uint2*)(HTH + swzb(c16, 2 * n0)) = uh;
            *(uint2*)(HTL + swzb(c16, 2 * n0)) = ul;
            h0 = f2bf(acc1[0]); l0 = f2bf(acc1[0] - bf2f(h0));
            h1 = f2bf(acc1[1]); l1 = f2bf(acc1[1] - bf2f(h1));
            h2 = f2bf(acc1[2]); l2 = f2bf(acc1[2] - bf2f(h2));
            h3 = f2bf(acc1[3]); l3 = f2bf(acc1[3] - bf2f(h3));
            uh.x = (uint)h0 | ((uint)h1 << 16); uh.y = (uint)h2 | ((uint)h3 << 16);
            ul.x = (uint)l0 | ((uint)l1 << 16); ul.y = (uint)l2 | ((uint)l3 << 16);
            *(uint2*)(HTH + swzb(16 + c16, 2 * n0)) = uh;
            *(uint2*)(HTL + swzb(16 + c16, 2 * n0)) = ul;
        }
        // es/ed: reduce acc*a over 32 o's (both halves pre-summed, 16-lane xor)
        const float as0 = ASV[c16], as1 = ASV[16 + c16];
        const float ad0 = ASV[32 + c16], ad1 = ASV[48 + c16];
        #pragma unroll
        for (int r = 0; r < 4; ++r) {
            float vs = acc0[r] * as0 + acc1[r] * as1;
            float vd = acc0[r] * ad0 + acc1[r] * ad1;
            #pragma unroll
            for (int mk = 1; mk <= 8; mk <<= 1) {
                vs += __shfl_xor(vs, mk, 64);
                vd += __shfl_xor(vd, mk, 64);
            }
            if (c16 == 0 && n0 + r < 100) { ESV[n0 + r] = vs; EDV[n0 + r] = vd; }
        }
    }
    __syncthreads();

    // ---- ph3a: in-register P, MFMA-2 accumulate; rowsum -> INV (LDS)
    f32x4 acc0 = {0.f, 0.f, 0.f, 0.f}, acc1 = {0.f, 0.f, 0.f, 0.f};
    if (w < 7) {
        const int np = w * 16 + c16;            // P-row this lane supplies (<=111)
        const float esn = ESV[np];
        const uint4 abv = *(const uint4*)(ABu + np * 4);
        float rowsum = 0.f;
        #pragma unroll
        for (int d = 0; d < 4; ++d) {
            const uint wrd = (d == 0) ? abv.x : (d == 1) ? abv.y : (d == 2) ? abv.z : abv.w;
            const float4 ea = *(const float4*)(EDV + d * 32 + r16 * 8);
            const float4 eb = *(const float4*)(EDV + d * 32 + r16 * 8 + 4);
            float p0, p1, p2, p3, p4, p5, p6, p7, e;
            e = esn + ea.x; e = e > 0.f ? e : 0.2f * e; p0 = ((wrd >> (r16 * 8 + 0)) & 1u) ? __expf(e) : 0.f;
            e = esn + ea.y; e = e > 0.f ? e : 0.2f * e; p1 = ((wrd >> (r16 * 8 + 1)) & 1u) ? __expf(e) : 0.f;
            e = esn + ea.z; e = e > 0.f ? e : 0.2f * e; p2 = ((wrd >> (r16 * 8 + 2)) & 1u) ? __expf(e) : 0.f;
            e = esn + ea.w; e = e > 0.f ? e : 0.2f * e; p3 = ((wrd >> (r16 * 8 + 3)) & 1u) ? __expf(e) : 0.f;
            e = esn + eb.x; e = e > 0.f ? e : 0.2f * e; p4 = ((wrd >> (r16 * 8 + 4)) & 1u) ? __expf(e) : 0.f;
            e = esn + eb.y; e = e > 0.f ? e : 0.2f * e; p5 = ((wrd >> (r16 * 8 + 5)) & 1u) ? __expf(e) : 0.f;
            e = esn + eb.z; e = e > 0.f ? e : 0.2f * e; p6 = ((wrd >> (r16 * 8 + 6)) & 1u) ? __expf(e) : 0.f;
            e = esn + eb.w; e = e > 0.f ? e : 0.2f * e; p7 = ((wrd >> (r16 * 8 + 7)) & 1u) ? __expf(e) : 0.f;
            rowsum += p0 + p1 + p2 + p3 + p4 + p5 + p6 + p7;
            ushort h0 = f2bf(p0), h1 = f2bf(p1), h2 = f2bf(p2), h3 = f2bf(p3);
            ushort h4 = f2bf(p4), h5 = f2bf(p5), h6 = f2bf(p6), h7 = f2bf(p7);
            ushort q0 = f2bf(p0 - bf2f(h0)), q1 = f2bf(p1 - bf2f(h1));
            ushort q2 = f2bf(p2 - bf2f(h2)), q3 = f2bf(p3 - bf2f(h3));
            ushort q4 = f2bf(p4 - bf2f(h4)), q5 = f2bf(p5 - bf2f(h5));
            ushort q6 = f2bf(p6 - bf2f(h6)), q7 = f2bf(p7 - bf2f(h7));
            short8 ph = mk8((uint)h0 | ((uint)h1 << 16), (uint)h2 | ((uint)h3 << 16),
                            (uint)h4 | ((uint)h5 << 16), (uint)h6 | ((uint)h7 << 16));
            short8 pl = mk8((uint)q0 | ((uint)q1 << 16), (uint)q2 | ((uint)q3 << 16),
                            (uint)q4 | ((uint)q5 << 16), (uint)q6 | ((uint)q7 << 16));
            const int kb = d * 64 + r16 * 16;
            short8 bh0 = *(const short8*)(HTH + swzb(c16, kb));
            short8 bl0 = *(const short8*)(HTL + swzb(c16, kb));
            short8 bh1 = *(const short8*)(HTH + swzb(16 + c16, kb));
            short8 bl1 = *(const short8*)(HTL + swzb(16 + c16, kb));
            acc0 = __builtin_amdgcn_mfma_f32_16x16x32_bf16(ph, bh0, acc0, 0, 0, 0);
            acc0 = __builtin_amdgcn_mfma_f32_16x16x32_bf16(ph, bl0, acc0, 0, 0, 0);
            acc0 = __builtin_amdgcn_mfma_f32_16x16x32_bf16(pl, bh0, acc0, 0, 0, 0);
            acc1 = __builtin_amdgcn_mfma_f32_16x16x32_bf16(ph, bh1, acc1, 0, 0, 0);
            acc1 = __builtin_amdgcn_mfma_f32_16x16x32_bf16(ph, bl1, acc1, 0, 0, 0);
            acc1 = __builtin_amdgcn_mfma_f32_16x16x32_bf16(pl, bh1, acc1, 0, 0, 0);
        }
        rowsum += __shfl_xor(rowsum, 16, 64);
        rowsum += __shfl_xor(rowsum, 32, 64);
        if (r16 == 0 && np < 100) INV[np] = 1.0f / rowsum;
    }
    __syncthreads();

    // ---- ph3b: epilogue elu(acc * inv) -> global
    if (w < 7) {
        const int n0 = w * 16 + r16 * 4;
        float* xo = xout + (size_t)b * Nn * Dd + hd * 32;
        #pragma unroll
        for (int r = 0; r < 4; ++r) {
            const int n = n0 + r;
            if (n < 100) {
                const float inv = INV[n];
                float v0 = acc0[r] * inv; v0 = v0 > 0.f ? v0 : expm1f(v0);
                float v1 = acc1[r] * inv; v1 = v1 > 0.f ? v1 : expm1f(v1);
                xo[(size_t)n * Dd + c16] = v0;
                xo[(size_t)n * Dd + 16 + c16] = v1;
            }
        }
    }
}

// ---------------------------------------------------------------------------
// GEMM1 split-bf16 MFMA, 128x128 tile, BK=64, SK=8 -> 512 blocks, 2/CU.
// B-staging: each 16B half gets its own swizzle-aware bofs() (R9 fix).
// ---------------------------------------------------------------------------
#define G1_LDS 73728
__device__ __forceinline__ int aofs(int r, int kb) { return r * 144 + kb; }
__device__ __forceinline__ int bofs(int n, int kb) { return n * 144 + (kb ^ (((n >> 3) & 1) << 4)); }

__global__ __launch_bounds__(512, 4) void gemm1_mfma(
    const float* __restrict__ Ag, const float* __restrict__ Bg,
    float* __restrict__ part)
{
    extern __shared__ char sm[];
    char* AH = sm;             // [128][144]
    char* AL = sm + 18432;
    char* BH = sm + 36864;     // [128][144]
    char* BL = sm + 55296;

    const int tid = threadIdx.x;
    const int pb = blockIdx.x;
    const int task = (pb & 7) * 64 + (pb >> 3);
    const int mb = task & 7, g = task >> 3;
    const int nb = g & 7, z = g >> 3;
    const int m0 = mb * 128, n0 = nb * 128;
    const int k0 = z * 1600;

    const int w = tid >> 6, lane = tid & 63;
    const int wn = w & 3, wm = w >> 2;               // wave tile 64m x 32n
    const int c16 = lane & 15, r16 = lane >> 4;

    const int ra = tid >> 2, kq = tid & 3;           // A: row, 16-k quarter
    const int bn = tid >> 2, kq4 = tid & 3;          // B: col n, 16-k quarter

    const float* Aptr = Ag + (size_t)(m0 + ra) * K1 + k0 + kq * 16;
    const float* Bptr = Bg + (size_t)(k0 + kq4 * 16) * N1 + n0 + bn;

    f32x4 acc[4][2];
    #pragma unroll
    for (int i = 0; i < 4; ++i)
        #pragma unroll
        for (int j = 0; j < 2; ++j) acc[i][j] = (f32x4){0.f, 0.f, 0.f, 0.f};

    float a_reg[16];
    float b_reg[16];
    #pragma unroll
    for (int q = 0; q < 4; ++q) *(float4*)&a_reg[q * 4] = *(const float4*)(Aptr + q * 4);
    #pragma unroll
    for (int j = 0; j < 16; ++j) b_reg[j] = Bptr[(size_t)j * N1];

    for (int it = 0; it < 25; ++it) {
        __syncthreads();   // previous iter's MFMA reads done -> LDS writable
        {
            uint hi[8], lo[8];
            #pragma unroll
            for (int i = 0; i < 8; ++i) {
                uint u0 = __float_as_uint(a_reg[2 * i]);
                uint u1 = __float_as_uint(a_reg[2 * i + 1]);
                float l0 = a_reg[2 * i]     - __uint_as_float(u0 & 0xFFFF0000u);
                float l1 = a_reg[2 * i + 1] - __uint_as_float(u1 & 0xFFFF0000u);
                hi[i] = __builtin_amdgcn_perm(u1, u0, 0x07060302u);
                lo[i] = __builtin_amdgcn_perm(__float_as_uint(l1), __float_as_uint(l0), 0x07060302u);
            }
            const int ab = aofs(ra, kq * 32);   // aofs has no XOR: +16 is safe
            *(uint4*)(AH + ab)      = make_uint4(hi[0], hi[1], hi[2], hi[3]);
            *(uint4*)(AH + ab + 16) = make_uint4(hi[4], hi[5], hi[6], hi[7]);
            *(uint4*)(AL + ab)      = make_uint4(lo[0], lo[1], lo[2], lo[3]);
            *(uint4*)(AL + ab + 16) = make_uint4(lo[4], lo[5], lo[6], lo[7]);
        }
        {
            uint hi[8], lo[8];
            #pragma unroll
            for (int i = 0; i < 8; ++i) {
                uint u0 = __float_as_uint(b_reg[2 * i]);
                uint u1 = __float_as_uint(b_reg[2 * i + 1]);
                float l0 = b_reg[2 * i]     - __uint_as_float(u0 & 0xFFFF0000u);
                float l1 = b_reg[2 * i + 1] - __uint_as_float(u1 & 0xFFFF0000u);
                hi[i] = __builtin_amdgcn_perm(u1, u0, 0x07060302u);
                lo[i] = __builtin_amdgcn_perm(__float_as_uint(l1), __float_as_uint(l0), 0x07060302u);
            }
            const int bb0 = bofs(bn, kq4 * 32);        // swizzle-aware per-16B
            const int bb1 = bofs(bn, kq4 * 32 + 16);
            *(uint4*)(BH + bb0) = make_uint4(hi[0], hi[1], hi[2], hi[3]);
            *(uint4*)(BH + bb1) = make_uint4(hi[4], hi[5], hi[6], hi[7]);
            *(uint4*)(BL + bb0) = make_uint4(lo[0], lo[1], lo[2], lo[3]);
            *(uint4*)(BL + bb1) = make_uint4(lo[4], lo[5], lo[6], lo[7]);
        }
        __syncthreads();   // LDS tile ready

        if (it < 24) {
            Aptr += 64;
            Bptr += (size_t)64 * N1;
            #pragma unroll
            for (int q = 0; q < 4; ++q) *(float4*)&a_reg[q * 4] = *(const float4*)(Aptr + q * 4);
            #pragma unroll
            for (int j = 0; j < 16; ++j) b_reg[j] = Bptr[(size_t)j * N1];
        }

        #pragma unroll
        for (int ks = 0; ks < 2; ++ks) {
            const int kb = ks * 64 + r16 * 16;
            short8 bh[2], bl[2];
            #pragma unroll
            for (int nf = 0; nf < 2; ++nf) {
                const int nr = wn * 32 + nf * 16 + c16;
                bh[nf] = *(const short8*)(BH + bofs(nr, kb));
                bl[nf] = *(const short8*)(BL + bofs(nr, kb));
            }
            #pragma unroll
            for (int mf = 0; mf < 4; ++mf) {
                const int ar = wm * 64 + mf * 16 + c16;
                short8 ah = *(const short8*)(AH + aofs(ar, kb));
                short8 al = *(const short8*)(AL + aofs(ar, kb));
                #pragma unroll
                for (int nf = 0; nf < 2; ++nf) {
                    acc[mf][nf] = __builtin_amdgcn_mfma_f32_16x16x32_bf16(ah, bh[nf], acc[mf][nf], 0, 0, 0);
                    acc[mf][nf] = __builtin_amdgcn_mfma_f32_16x16x32_bf16(al, bh[nf], acc[mf][nf], 0, 0, 0);
                    acc[mf][nf] = __builtin_amdgcn_mfma_f32_16x16x32_bf16(ah, bl[nf], acc[mf][nf], 0, 0, 0);
                }
            }
        }
    }

    float* pz = part + (size_t)z * M1 * N1;
    #pragma unroll
    for (int mf = 0; mf < 4; ++mf) {
        const int m = m0 + wm * 64 + mf * 16 + r16 * 4;
        #pragma unroll
        for (int nf = 0; nf < 2; ++nf) {
            const int n = n0 + wn * 32 + nf * 16 + c16;
            #pragma unroll
            for (int r = 0; r < 4; ++r)
                pz[(size_t)(m + r) * N1 + n] = acc[mf][nf][r];
        }
    }
}

// Reduce split-K partials + bias + BN(eval) + ReLU
__global__ __launch_bounds__(256) void bn1_reduce(
    const float* __restrict__ part, const float* __restrict__ pb1,
    const float* __restrict__ g1, const float* __restrict__ be1,
    float* __restrict__ y1)
{
    const int idx = blockIdx.x * 256 + threadIdx.x;
    float s = 0.f;
    #pragma unroll
    for (int z = 0; z < SK; ++z) s += part[(size_t)z * M1 * N1 + idx];
    const int j = idx & (N1 - 1);
    s += pb1[j];
    const float rbn = 1.0f / sqrtf(1.0f + 1e-5f);
    s = g1[j] * s * rbn + be1[j];
    y1[idx] = fmaxf(s, 0.f);
}

// GEMM2 (1024x1024)x(1024x128) + bias + BN + ReLU -> d_out
__global__ __launch_bounds__(128) void gemm2_bn(
    const float* __restrict__ y1, const float* __restrict__ W2,
    const float* __restrict__ pb2, const float* __restrict__ g2,
    const float* __restrict__ be2, float* __restrict__ out)
{
    __shared__ __align__(16) float xr[1024];
    const int tid = threadIdx.x, m = blockIdx.x;
    for (int i = tid; i < 1024; i += 128) xr[i] = y1[(size_t)m * 1024 + i];
    __syncthreads();
    float acc = 0.f;
    #pragma unroll 8
    for (int k = 0; k < 1024; ++k) acc += xr[k] * W2[k * 128 + tid];
    acc += pb2[tid];
    const float rbn = 1.0f / sqrtf(1.0f + 1e-5f);
    acc = g2[tid] * acc * rbn + be2[tid];
    out[(size_t)m * 128 + tid] = fmaxf(acc, 0.f);
}

// ---------------------------------------------------------------------------
extern "C" void kernel_launch(void* const* d_in, const int* in_sizes, int n_in,
                              void* d_out, int out_size, void* d_ws, size_t ws_size,
                              hipStream_t stream)
{
    const float* X   = (const float*)d_in[0];
    const float* A   = (const float*)d_in[1];
    const float* W0  = (const float*)d_in[2];
    const float* a0  = (const float*)d_in[3];
    const float* Wl  = (const float*)d_in[4];
    const float* al  = (const float*)d_in[5];
    const float* pW1 = (const float*)d_in[6];
    const float* pb1 = (const float*)d_in[7];
    const float* g1  = (const float*)d_in[8];
    const float* be1 = (const float*)d_in[9];
    const float* pW2 = (const float*)d_in[10];
    const float* pb2 = (const float*)d_in[11];
    const float* g2  = (const float*)d_in[12];
    const float* be2 = (const float*)d_in[13];
    float* out = (float*)d_out;

    // ws: xa(52.4MB) | xb(52.4MB, reused as gemm1 partials) | y1(4.2MB, AW overlay)
    float* ws = (float*)d_ws;
    float* xa = ws;
    float* xb = xa + (size_t)Bb * Nn * Dd;
    float* y1 = xb + (size_t)Bb * Nn * Dd;
    float* part = xb;
    uint*  AW = (uint*)y1;          // packed adjacency, dead before bn1 writes y1

    (void)hipFuncSetAttribute(reinterpret_cast<const void*>(gat_fused<65, 3>),
                              hipFuncAttributeMaxDynamicSharedMemorySize, GAT_LDS);
    (void)hipFuncSetAttribute(reinterpret_cast<const void*>(gat_fused<128, 4>),
                              hipFuncAttributeMaxDynamicSharedMemorySize, GAT_LDS);
    (void)hipFuncSetAttribute(reinterpret_cast<const void*>(gemm1_mfma),
                              hipFuncAttributeMaxDynamicSharedMemorySize, G1_LDS);

    pack_A<<<dim3(Bb), 256, 0, stream>>>(A, AW);
    gat_fused<65, 3><<<dim3(Bb * Hh), 512, GAT_LDS, stream>>>(X, AW, W0, a0, xa);
    const float* src = xa; float* dst = xb;
    for (int l = 1; l < 5; ++l) {
        gat_fused<128, 4><<<dim3(Bb * Hh), 512, GAT_LDS, stream>>>(
            src, AW, Wl + (size_t)(l - 1) * Hh * Dd * Oo, al + (size_t)(l - 1) * Hh * 2 * Oo, dst);
        float* t = (float*)src; src = dst; dst = t;
    }
    gemm1_mfma<<<dim3(512), 512, G1_LDS, stream>>>(src, pW1, part);
    bn1_reduce<<<dim3((M1 * N1) / 256), 256, 0, stream>>>(part, pb1, g1, be1, y1);
    gemm2_bn<<<dim3(M1), 128, 0, stream>>>(y1, pW2, pb2, g2, be2, out);
}